// Round 8
// baseline (1451.856 us; speedup 1.0000x reference)
//
#include <hip/hip_runtime.h>
#include <hip/hip_bf16.h>
#include <cstdint>

// Problem constants
constexpr int NB_ = 32;     // batch
constexpr int NS_ = 512;    // text length S
constexpr int NT_ = 2048;   // mel length T
constexpr int DMEL = 80;    // embedding dim

// ---------------- workspace layout ----------------
constexpr size_t P = 134217728ull;  // persistent block base
constexpr size_t PO_TE   = 0ull;
constexpr size_t PO_ME   = 5242880ull;
constexpr size_t PO_NA   = 26214400ull;
constexpr size_t PO_NB   = 26279936ull;
constexpr size_t PO_M    = 26542080ull;
constexpr size_t PO_RZ   = 26804224ull;
constexpr size_t PO_W1   = 27066368ull;
constexpr size_t PO_W2   = 28639232ull;
constexpr size_t PO_W3   = 28803072ull;
constexpr size_t PO_W4   = 28956672ull;
constexpr size_t PO_W5   = 29110272ull;
constexpr size_t PO_BIAS = 29135872ull;
constexpr size_t PO_DIR  = 29139968ull;
constexpr size_t PO_IDX  = 33334272ull;
constexpr size_t PO_FLAG = 33334400ull;
constexpr size_t FULL_NEED = P + 33334528ull;

constexpr int BO_T1 = 0, BO_T2 = 512, BO_M1 = 592, BO_M2 = 752, BO_M3 = 832;

// ---------------- dtype detect: bf16 vs f32 probe on text ----------------
__global__ void k_detect(const uint32_t* __restrict__ w, int* __restrict__ flag) {
  __shared__ int red[256];
  const int tid = threadIdx.x;
  int cnt = 0;
  for (int i = tid; i < 4096; i += 256) {
    uint32_t e = (w[i] >> 7) & 0xFFu;
    cnt += (e >= 119u && e <= 129u) ? 1 : 0;
  }
  red[tid] = cnt;
  __syncthreads();
  for (int s = 128; s > 0; s >>= 1) {
    if (tid < s) red[tid] += red[tid + s];
    __syncthreads();
  }
  if (tid == 0) *flag = (red[0] > 2048) ? 1 : 0;
}

// ---------------- flag-branched convert to f32 ----------------
__global__ void k_cvt(const void* __restrict__ in, float* __restrict__ out, int n,
                      const int* __restrict__ flag) {
  const int i = blockIdx.x * 256 + threadIdx.x;
  if (i >= n) return;
  if (*flag) {
    uint16_t u = ((const uint16_t*)in)[i];
    out[i] = __uint_as_float((uint32_t)u << 16);
  } else {
    out[i] = ((const float*)in)[i];
  }
}

// ---------------- weight transpose ----------------
__global__ void k_wtrans(const void* __restrict__ w, float* __restrict__ wT,
                         int CO, int CI, int KW, int total, const int* __restrict__ flag) {
  int id = blockIdx.x * 256 + threadIdx.x;
  if (id >= total) return;
  int co = id % CO;
  int rest = id / CO;
  int ci = rest % CI;
  int tap = rest / CI;
  int src = (co * CI + ci) * KW + tap;
  if (*flag) {
    uint16_t u = ((const uint16_t*)w)[src];
    wT[id] = __uint_as_float((uint32_t)u << 16);
  } else {
    wT[id] = ((const float*)w)[src];
  }
}

// ---------------- conv1d as implicit GEMM (pure f32) ----------------
template <int CIN, int KW, int COUT, int NTILE, int NR, int KC, int LOG2L, int ACT, bool MASK>
__global__ __launch_bounds__(256) void k_conv(const float* __restrict__ x,
                                              const float* __restrict__ wT,
                                              const float* __restrict__ bias,
                                              float* __restrict__ y,
                                              const int* __restrict__ lenArr) {
  constexpr int L = 1 << LOG2L;
  constexpr int PAD = (KW - 1) / 2;
  constexpr int MT = 128;
  constexpr int APAD = 132;
  constexpr int BPAD = NTILE + 4;
  __shared__ float As[KC][APAD];
  __shared__ float Bs[KC][BPAD];

  const int tid = threadIdx.x;
  const int tx = tid & 15;
  const int ty = tid >> 4;
  constexpr int NBLK = COUT / NTILE;
  const int m0 = (blockIdx.x / NBLK) * MT;
  const int n0 = (blockIdx.x % NBLK) * NTILE;

  float acc[8][NR];
#pragma unroll
  for (int i = 0; i < 8; ++i)
#pragma unroll
    for (int j = 0; j < NR; ++j) acc[i][j] = 0.f;

  for (int tap = 0; tap < KW; ++tap) {
    for (int k0 = 0; k0 < CIN; k0 += KC) {
      __syncthreads();
      constexpr int AF4 = MT * KC / 4;
      constexpr int F4R = KC / 4;
      for (int f = tid; f < AF4; f += 256) {
        int row = f / F4R;
        int ko = (f % F4R) * 4;
        int r = m0 + row;
        int b = r >> LOG2L;
        int pos = (r & (L - 1)) + tap - PAD;
        float4 v = make_float4(0.f, 0.f, 0.f, 0.f);
        if (pos >= 0 && pos < L)
          v = *reinterpret_cast<const float4*>(
              &x[((size_t)(b << LOG2L) + pos) * CIN + k0 + ko]);
        As[ko + 0][row] = v.x;
        As[ko + 1][row] = v.y;
        As[ko + 2][row] = v.z;
        As[ko + 3][row] = v.w;
      }
      constexpr int BF4 = KC * NTILE / 4;
      constexpr int BF4R = NTILE / 4;
      for (int f = tid; f < BF4; f += 256) {
        int kk = f / BF4R;
        int no = (f % BF4R) * 4;
        float4 v = *reinterpret_cast<const float4*>(
            &wT[((size_t)(tap * CIN + k0 + kk)) * COUT + n0 + no]);
        *reinterpret_cast<float4*>(&Bs[kk][no]) = v;
      }
      __syncthreads();
#pragma unroll 8
      for (int kk = 0; kk < KC; ++kk) {
        float4 a0 = *reinterpret_cast<const float4*>(&As[kk][ty * 8]);
        float4 a1 = *reinterpret_cast<const float4*>(&As[kk][ty * 8 + 4]);
        float av[8] = {a0.x, a0.y, a0.z, a0.w, a1.x, a1.y, a1.z, a1.w};
        float bv[NR];
#pragma unroll
        for (int j = 0; j < NR; ++j) bv[j] = Bs[kk][tx * NR + j];
#pragma unroll
        for (int i = 0; i < 8; ++i)
#pragma unroll
          for (int j = 0; j < NR; ++j) acc[i][j] = fmaf(av[i], bv[j], acc[i][j]);
      }
    }
  }
#pragma unroll
  for (int i = 0; i < 8; ++i) {
    int r = m0 + ty * 8 + i;
    int b = r >> LOG2L;
    int pos = r & (L - 1);
    bool zero = MASK && (pos >= lenArr[b]);
#pragma unroll
    for (int j = 0; j < NR; ++j) {
      int c = n0 + tx * NR + j;
      float v = acc[i][j] + bias[c];
      if (ACT == 1) v = fmaxf(v, 0.f);
      if (ACT == 2) v = (v >= 0.f) ? v : 0.01f * v;
      if (zero) v = 0.f;
      y[(size_t)r * COUT + c] = v;
    }
  }
}

// ---------------- row squared-norms ----------------
__global__ void k_norms(const float* __restrict__ e, float* __restrict__ out, int rows) {
  int tid = blockIdx.x * 256 + threadIdx.x;
  int row = tid >> 2, sub = tid & 3;
  if (row >= rows) return;
  const float* p = e + (size_t)row * DMEL;
  float s = 0.f;
#pragma unroll
  for (int j = 0; j < 5; ++j) {
    float4 v = *reinterpret_cast<const float4*>(&p[(sub + 4 * j) * 4]);
    s = fmaf(v.x, v.x, fmaf(v.y, v.y, fmaf(v.z, v.z, fmaf(v.w, v.w, s))));
  }
  s += __shfl_xor(s, 1);
  s += __shfl_xor(s, 2);
  if (sub == 0) out[row] = s;
}

// ---------------- softmax stats by recomputation ----------------
__global__ __launch_bounds__(256) void k_stats2(
    const float* __restrict__ te, const float* __restrict__ me,
    const float* __restrict__ na, const float* __restrict__ nb,
    const int* __restrict__ src_len, const int* __restrict__ mel_len,
    float* __restrict__ marr, float* __restrict__ rzarr) {
  const int b = blockIdx.x >> 5;
  const int t0 = (blockIdx.x & 31) << 6;
  __shared__ float Bt[DMEL][68];
  __shared__ float At[DMEL][68];
  __shared__ float redm[16][64];
  __shared__ float redz[16][64];
  const int tid = threadIdx.x;
  for (int f = tid; f < 64 * 20; f += 256) {
    int row = f / 20, ko = (f % 20) << 2;
    float4 v = *reinterpret_cast<const float4*>(
        &me[((size_t)b * NT_ + t0 + row) * DMEL + ko]);
    Bt[ko][row] = v.x; Bt[ko + 1][row] = v.y; Bt[ko + 2][row] = v.z; Bt[ko + 3][row] = v.w;
  }
  const int tx = tid & 15, sy = tid >> 4;
  const int sl = src_len[b], ml = mel_len[b];
  const float NEGINF = -__builtin_inff();
  float nbv[4], mACC[4], zACC[4];
#pragma unroll
  for (int j = 0; j < 4; ++j) {
    nbv[j] = nb[b * NT_ + t0 + (tx << 2) + j];
    mACC[j] = NEGINF;
    zACC[j] = 0.f;
  }
  for (int c = 0; c < 8; ++c) {
    const int s0 = c << 6;
    __syncthreads();
    for (int f = tid; f < 64 * 20; f += 256) {
      int row = f / 20, ko = (f % 20) << 2;
      float4 v = *reinterpret_cast<const float4*>(
          &te[((size_t)b * NS_ + s0 + row) * DMEL + ko]);
      At[ko][row] = v.x; At[ko + 1][row] = v.y; At[ko + 2][row] = v.z; At[ko + 3][row] = v.w;
    }
    __syncthreads();
    float acc[4][4];
#pragma unroll
    for (int i = 0; i < 4; ++i)
#pragma unroll
      for (int j = 0; j < 4; ++j) acc[i][j] = 0.f;
#pragma unroll 8
    for (int kk = 0; kk < DMEL; ++kk) {
      float4 a = *reinterpret_cast<const float4*>(&At[kk][sy << 2]);
      float4 bb = *reinterpret_cast<const float4*>(&Bt[kk][tx << 2]);
      float av[4] = {a.x, a.y, a.z, a.w}, bv[4] = {bb.x, bb.y, bb.z, bb.w};
#pragma unroll
      for (int i = 0; i < 4; ++i)
#pragma unroll
        for (int j = 0; j < 4; ++j) acc[i][j] = fmaf(av[i], bv[j], acc[i][j]);
    }
    float nav[4];
#pragma unroll
    for (int i = 0; i < 4; ++i) nav[i] = na[b * NS_ + s0 + (sy << 2) + i];
#pragma unroll
    for (int j = 0; j < 4; ++j) {
      const bool tvalid = (t0 + (tx << 2) + j) < ml;
      float ov[4];
      float mNew = mACC[j];
#pragma unroll
      for (int i = 0; i < 4; ++i) {
        float d2 = (nav[i] + nbv[j]) - 2.0f * acc[i][j];
        float dist = sqrtf(fmaxf(d2, 1e-12f));
        bool valid = ((s0 + (sy << 2) + i) < sl) && tvalid;
        ov[i] = valid ? -dist : -1e9f;
        mNew = fmaxf(mNew, ov[i]);
      }
      float scale = expf(mACC[j] - mNew);
      float zadd = 0.f;
#pragma unroll
      for (int i = 0; i < 4; ++i) zadd += expf(ov[i] - mNew);
      zACC[j] = zACC[j] * scale + zadd;
      mACC[j] = mNew;
    }
  }
#pragma unroll
  for (int j = 0; j < 4; ++j) {
    redm[sy][(tx << 2) + j] = mACC[j];
    redz[sy][(tx << 2) + j] = zACC[j];
  }
  __syncthreads();
  if (tid < 64) {
    float M = NEGINF, Z = 0.f;
#pragma unroll
    for (int y = 0; y < 16; ++y) {
      float m = redm[y][tid], z = redz[y][tid];
      float Mn = fmaxf(M, m);
      Z = Z * expf(M - Mn) + z * expf(m - Mn);
      M = Mn;
    }
    marr[b * NT_ + t0 + tid] = M;
    rzarr[b * NT_ + t0 + tid] = 1.0f / Z;
  }
}

// ---------------- finalize: soft/rev f32 out + f32 val for DP ----------------
__global__ __launch_bounds__(256) void k_final3(
    const float* __restrict__ te, const float* __restrict__ me,
    const float* __restrict__ na, const float* __restrict__ nb,
    const float* __restrict__ marr, const float* __restrict__ rzarr,
    const int* __restrict__ src_len, const int* __restrict__ mel_len,
    float* __restrict__ val,
    float* __restrict__ soft, float* __restrict__ rev) {
  const int idx = blockIdx.x;
  const int tt = idx & 31;
  const int st = (idx >> 5) & 7;
  const int b = idx >> 8;
  const int s0 = st << 6, t0 = tt << 6;
  __shared__ float At[DMEL][68];
  __shared__ float Bt[DMEL][68];
  __shared__ float pl[64][65];
  const int tid = threadIdx.x;
  for (int f = tid; f < 64 * 20; f += 256) {
    int row = f / 20, ko = (f % 20) << 2;
    float4 v = *reinterpret_cast<const float4*>(
        &te[((size_t)b * NS_ + s0 + row) * DMEL + ko]);
    At[ko][row] = v.x; At[ko + 1][row] = v.y; At[ko + 2][row] = v.z; At[ko + 3][row] = v.w;
  }
  for (int f = tid; f < 64 * 20; f += 256) {
    int row = f / 20, ko = (f % 20) << 2;
    float4 v = *reinterpret_cast<const float4*>(
        &me[((size_t)b * NT_ + t0 + row) * DMEL + ko]);
    Bt[ko][row] = v.x; Bt[ko + 1][row] = v.y; Bt[ko + 2][row] = v.z; Bt[ko + 3][row] = v.w;
  }
  __syncthreads();
  const int tx = tid & 15, sy = tid >> 4;
  float acc[4][4];
#pragma unroll
  for (int i = 0; i < 4; ++i)
#pragma unroll
    for (int j = 0; j < 4; ++j) acc[i][j] = 0.f;
#pragma unroll 8
  for (int kk = 0; kk < DMEL; ++kk) {
    float4 a = *reinterpret_cast<const float4*>(&At[kk][sy << 2]);
    float4 bb = *reinterpret_cast<const float4*>(&Bt[kk][tx << 2]);
    float av[4] = {a.x, a.y, a.z, a.w}, bv[4] = {bb.x, bb.y, bb.z, bb.w};
#pragma unroll
    for (int i = 0; i < 4; ++i)
#pragma unroll
      for (int j = 0; j < 4; ++j) acc[i][j] = fmaf(av[i], bv[j], acc[i][j]);
  }
  const int sl = src_len[b], ml = mel_len[b];
  float nav[4], nbv[4];
#pragma unroll
  for (int i = 0; i < 4; ++i) nav[i] = na[b * NS_ + s0 + (sy << 2) + i];
#pragma unroll
  for (int j = 0; j < 4; ++j) nbv[j] = nb[b * NT_ + t0 + (tx << 2) + j];
#pragma unroll
  for (int j = 0; j < 4; ++j) {
    const int t = t0 + (tx << 2) + j;
    const bool tvalid = t < ml;
    const float mv = marr[b * NT_ + t];
    const float rzv = rzarr[b * NT_ + t];
    float pv[4];
#pragma unroll
    for (int i = 0; i < 4; ++i) {
      float d2 = (nav[i] + nbv[j]) - 2.0f * acc[i][j];
      float dist = sqrtf(fmaxf(d2, 1e-12f));
      bool valid = ((s0 + (sy << 2) + i) < sl) && tvalid;
      float ov = valid ? -dist : -1e9f;
      float p = tvalid ? expf(ov - mv) * rzv : 0.f;
      pv[i] = p;
      pl[(tx << 2) + j][(sy << 2) + i] = p;
    }
    float4 o = make_float4(pv[0], pv[1], pv[2], pv[3]);
    *reinterpret_cast<float4*>(&val[((size_t)b * NT_ + t) * NS_ + s0 + (sy << 2)]) = o;
  }
  __syncthreads();
  const int lane = tid & 63, w = tid >> 6;
#pragma unroll 4
  for (int i = 0; i < 16; ++i) {
    const int s_loc = (w << 4) + i;
    const int s = s0 + s_loc;
    float p = pl[lane][s_loc];
    size_t o = ((size_t)b * NS_ + s) * NT_ + t0 + lane;
    soft[o] = p;
    bool r = (s >= sl) || ((t0 + lane) >= ml);
    rev[o] = r ? 1.0f : 0.0f;
  }
}

// ---------------- async global->LDS 16B helper ----------------
__device__ __forceinline__ void dp_issue16(const float* g, float* l) {
  __builtin_amdgcn_global_load_lds(
      (const __attribute__((address_space(1))) void*)g,
      (__attribute__((address_space(3))) void*)l, 16, 0, 0);
}

// ---------------- DP forward scan: 1 consumer + 4 producer waves ----------------
// LDS layout per row (512 floats): de-interleaved via pre-swizzled global source
// (rule 21): LDS[0..255] holds even 16B-chunks (floats 8k..8k+3), LDS[256..511]
// holds odd chunks (floats 8k+4..8k+7). Consumer reads row[lane*4] and
// row[256+lane*4] -> linear b128 across lanes = bank-conflict-free, and lane
// still owns floats [8*lane, 8*lane+8).
__global__ __launch_bounds__(320) void k_dp(const float* __restrict__ val,
                                            const int* __restrict__ src_len,
                                            const int* __restrict__ mel_len,
                                            uint32_t* __restrict__ dir) {
  __shared__ float buf[2][16][512];  // 64 KB double buffer
  const int b = blockIdx.x;
  const int wv = threadIdx.x >> 6;   // 0 = consumer, 1..4 = producers
  const int lane = threadIdx.x & 63;
  const float* base = val + (size_t)b * NT_ * NS_;
  const int sl = src_len[b];
  const int ml = mel_len[b];
  const float NEGINF = -__builtin_inff();

  float v[8];
#pragma unroll
  for (int j = 0; j < 8; ++j) v[j] = 0.0f;
  uint32_t bw[8];
#pragma unroll
  for (int j = 0; j < 8; ++j) bw[j] = 0u;

  // prologue: producers stage chunk 0 (4 rows each)
  if (wv > 0) {
#pragma unroll
    for (int rr = 0; rr < 4; ++rr) {
      const int r = ((wv - 1) << 2) + rr;
      const float* g = base + (size_t)r * NS_ + (lane << 3);
      dp_issue16(g, &buf[0][r][0]);        // even chunks -> first half
      dp_issue16(g + 4, &buf[0][r][256]);  // odd chunks  -> second half
    }
    asm volatile("s_waitcnt vmcnt(0)" ::: "memory");
  }
  __syncthreads();

  for (int c = 0; c < 128; ++c) {
    if (wv > 0) {
      // producers: stage chunk c+1 into the other buffer, drain own vmcnt
      if (c + 1 < 128) {
        const int pb = (c + 1) & 1;
        const float* cb = base + (size_t)(c + 1) * 16 * NS_;
#pragma unroll
        for (int rr = 0; rr < 4; ++rr) {
          const int r = ((wv - 1) << 2) + rr;
          const float* g = cb + (size_t)r * NS_ + (lane << 3);
          dp_issue16(g, &buf[pb][r][0]);
          dp_issue16(g + 4, &buf[pb][r][256]);
        }
      }
      asm volatile("s_waitcnt vmcnt(0)" ::: "memory");
    } else {
      // consumer: compute 16 rows of chunk c
      const float* rowbase = &buf[c & 1][0][0];
      const int tbase = c << 4;
#pragma unroll
      for (int r = 0; r < 16; ++r) {
        const float* rp = rowbase + (r << 9);
        float4 c0 = *reinterpret_cast<const float4*>(rp + (lane << 2));
        float4 c1 = *reinterpret_cast<const float4*>(rp + 256 + (lane << 2));
        float cc[8] = {c0.x, c0.y, c0.z, c0.w, c1.x, c1.y, c1.z, c1.w};
        const int t = tbase + r;
        float up = __shfl_up(v[7], 1);
        float prev = (lane == 0) ? NEGINF : up;
        const bool tml = t < ml;
        const int sh = t & 31;
#pragma unroll
        for (int j = 0; j < 8; ++j) {
          float cur = v[j];
          bool keep = cur >= prev;
          float vm = keep ? cur : prev;
          int s = (lane << 3) + j;
          float vn = (s <= t) ? vm + cc[j] : NEGINF;
          bool bit = (tml && (s < sl)) ? keep : true;
          bw[j] |= (uint32_t)bit << sh;
          v[j] = vn;
          prev = cur;
        }
      }
      if (c & 1) {  // 32 rows accumulated -> store direction words
        const int c32 = c >> 1;
#pragma unroll
        for (int j = 0; j < 8; ++j) {
          dir[((size_t)(b * NS_) + (lane << 3) + j) * 64 + c32] = bw[j];
          bw[j] = 0u;
        }
      }
    }
    __syncthreads();
  }
}

// ---------------- backtrack (two half-T phases) ----------------
__global__ __launch_bounds__(256) void k_backtrack(
    const uint32_t* __restrict__ dir, const int* __restrict__ src_len,
    const int* __restrict__ mel_len, float* __restrict__ hard,
    int* __restrict__ idxio, int phase) {
  __shared__ uint32_t dl[NS_ * 32];
  const int b = blockIdx.x, tid = threadIdx.x;
  const uint32_t* db = dir + (size_t)b * NS_ * 64;
  const int woff = phase ? 0 : 32;
  for (int f = tid; f < 4096; f += 256) {
    int s = f >> 3;
    int wo = (f & 7) << 2;
    *reinterpret_cast<uint4*>(&dl[s * 32 + wo]) =
        *reinterpret_cast<const uint4*>(&db[s * 64 + woff + wo]);
  }
  __syncthreads();
  if (tid == 0) {
    const int ml = mel_len[b];
    int idx = phase ? idxio[b] : (src_len[b] - 1);
    if (idx < 0) idx = 0;
    if (idx > NS_ - 1) idx = NS_ - 1;
    const int thi = phase ? 1023 : 2047;
    const int tlo = phase ? 0 : 1024;
    int cw = -1, ci = -1;
    uint32_t w = 0;
    for (int t = thi; t >= tlo; --t) {
      int wi = t >> 5;
      if (wi != cw || idx != ci) {
        w = dl[idx * 32 + (wi - woff)];
        cw = wi;
        ci = idx;
      }
      if (t < ml) hard[((size_t)(b * NS_) + idx) * NT_ + t] = 1.0f;
      int step = (int)((w >> (t & 31)) & 1) - 1;
      idx += step;
      if (idx < 0) idx = 0;
    }
    if (!phase) idxio[b] = idx;
  }
}

// ---------------- host launch ----------------
extern "C" void kernel_launch(void* const* d_in, const int* in_sizes, int n_in,
                              void* d_out, int out_size, void* d_ws, size_t ws_size,
                              hipStream_t stream) {
  if (n_in != 17) return;
  if (ws_size < FULL_NEED) return;

  const void* text = d_in[0];
  const void* mel = d_in[1];
  const int* src_len = (const int*)d_in[2];
  const int* mel_len = (const int*)d_in[3];
  const void* tw1 = d_in[7];
  const void* tb1 = d_in[8];
  const void* tw2 = d_in[9];
  const void* tb2 = d_in[10];
  const void* mw1 = d_in[11];
  const void* mb1 = d_in[12];
  const void* mw2 = d_in[13];
  const void* mb2 = d_in[14];
  const void* mw3 = d_in[15];
  const void* mb3 = d_in[16];

  char* w8 = (char*)d_ws;
  float* mel_f32 = (float*)(w8 + 0);
  float* melh1 = (float*)(w8 + 20971520ull);
  float* mh2 = (float*)(w8 + 62914560ull);
  float* text_f32 = (float*)(w8 + 83886080ull);
  float* texth1 = (float*)(w8 + 100663296ull);
  float* val = (float*)(w8 + 0);

  float* te = (float*)(w8 + P + PO_TE);
  float* me = (float*)(w8 + P + PO_ME);
  float* na = (float*)(w8 + P + PO_NA);
  float* nb = (float*)(w8 + P + PO_NB);
  float* marr = (float*)(w8 + P + PO_M);
  float* rzarr = (float*)(w8 + P + PO_RZ);
  float* wt1 = (float*)(w8 + P + PO_W1);
  float* wt2 = (float*)(w8 + P + PO_W2);
  float* wt3 = (float*)(w8 + P + PO_W3);
  float* wt4 = (float*)(w8 + P + PO_W4);
  float* wt5 = (float*)(w8 + P + PO_W5);
  float* biasb = (float*)(w8 + P + PO_BIAS);
  uint32_t* dir = (uint32_t*)(w8 + P + PO_DIR);
  int* idxio = (int*)(w8 + P + PO_IDX);
  int* flag = (int*)(w8 + P + PO_FLAG);

  // outputs are float32
  float* soft = (float*)d_out;
  float* hard = soft + (size_t)NB_ * NS_ * NT_;
  float* rev = soft + 2 * (size_t)NB_ * NS_ * NT_;

  // dtype detect + converts
  k_detect<<<1, 256, 0, stream>>>((const uint32_t*)text, flag);
  k_cvt<<<(NB_ * NS_ * 256 + 255) / 256, 256, 0, stream>>>(text, text_f32, NB_ * NS_ * 256, flag);
  k_cvt<<<(NB_ * NT_ * 80 + 255) / 256, 256, 0, stream>>>(mel, mel_f32, NB_ * NT_ * 80, flag);
  k_cvt<<<2, 256, 0, stream>>>(tb1, biasb + BO_T1, 512, flag);
  k_cvt<<<1, 256, 0, stream>>>(tb2, biasb + BO_T2, 80, flag);
  k_cvt<<<1, 256, 0, stream>>>(mb1, biasb + BO_M1, 160, flag);
  k_cvt<<<1, 256, 0, stream>>>(mb2, biasb + BO_M2, 80, flag);
  k_cvt<<<1, 256, 0, stream>>>(mb3, biasb + BO_M3, 80, flag);

  // weight transposes
  k_wtrans<<<(512 * 256 * 3 + 255) / 256, 256, 0, stream>>>(tw1, wt1, 512, 256, 3, 512 * 256 * 3, flag);
  k_wtrans<<<(80 * 512 + 255) / 256, 256, 0, stream>>>(tw2, wt2, 80, 512, 1, 80 * 512, flag);
  k_wtrans<<<(160 * 80 * 3 + 255) / 256, 256, 0, stream>>>(mw1, wt3, 160, 80, 3, 160 * 80 * 3, flag);
  k_wtrans<<<(80 * 160 * 3 + 255) / 256, 256, 0, stream>>>(mw2, wt4, 80, 160, 3, 80 * 160 * 3, flag);
  k_wtrans<<<(80 * 80 + 255) / 256, 256, 0, stream>>>(mw3, wt5, 80, 80, 1, 80 * 80, flag);

  // encoders (pure f32)
  k_conv<80, 3, 160, 80, 5, 16, 11, 2, false><<<512 * 2, 256, 0, stream>>>(mel_f32, wt3, biasb + BO_M1, melh1, nullptr);
  k_conv<160, 3, 80, 80, 5, 32, 11, 2, false><<<512 * 1, 256, 0, stream>>>(melh1, wt4, biasb + BO_M2, mh2, nullptr);
  k_conv<80, 1, 80, 80, 5, 16, 11, 0, true><<<512 * 1, 256, 0, stream>>>(mh2, wt5, biasb + BO_M3, me, mel_len);
  k_conv<256, 3, 512, 64, 4, 32, 9, 1, false><<<128 * 8, 256, 0, stream>>>(text_f32, wt1, biasb + BO_T1, texth1, nullptr);
  k_conv<512, 1, 80, 80, 5, 32, 9, 0, true><<<128 * 1, 256, 0, stream>>>(texth1, wt2, biasb + BO_T2, te, src_len);

  // norms
  k_norms<<<(NB_ * NS_ * 4) / 256, 256, 0, stream>>>(te, na, NB_ * NS_);
  k_norms<<<(NB_ * NT_ * 4) / 256, 256, 0, stream>>>(me, nb, NB_ * NT_);

  // softmax stats + finalize
  k_stats2<<<NB_ * 32, 256, 0, stream>>>(te, me, na, nb, src_len, mel_len, marr, rzarr);
  k_final3<<<NB_ * 8 * 32, 256, 0, stream>>>(te, me, na, nb, marr, rzarr, src_len, mel_len,
                                             val, soft, rev);

  // hard_A
  hipMemsetAsync(hard, 0, (size_t)NB_ * NS_ * NT_ * 4, stream);
  k_dp<<<NB_, 320, 0, stream>>>(val, src_len, mel_len, dir);
  k_backtrack<<<NB_, 256, 0, stream>>>(dir, src_len, mel_len, hard, idxio, 0);
  k_backtrack<<<NB_, 256, 0, stream>>>(dir, src_len, mel_len, hard, idxio, 1);
}

// Round 9
// 1408.028 us; speedup vs baseline: 1.0311x; 1.0311x over previous
//
#include <hip/hip_runtime.h>
#include <hip/hip_bf16.h>
#include <cstdint>

// Problem constants
constexpr int NB_ = 32;     // batch
constexpr int NS_ = 512;    // text length S
constexpr int NT_ = 2048;   // mel length T
constexpr int DMEL = 80;    // embedding dim

// ---------------- workspace layout ----------------
constexpr size_t P = 134217728ull;  // persistent block base
constexpr size_t PO_TE   = 0ull;
constexpr size_t PO_ME   = 5242880ull;
constexpr size_t PO_NA   = 26214400ull;
constexpr size_t PO_NB   = 26279936ull;
constexpr size_t PO_M    = 26542080ull;
constexpr size_t PO_RZ   = 26804224ull;
constexpr size_t PO_W1   = 27066368ull;
constexpr size_t PO_W2   = 28639232ull;
constexpr size_t PO_W3   = 28803072ull;
constexpr size_t PO_W4   = 28956672ull;
constexpr size_t PO_W5   = 29110272ull;
constexpr size_t PO_BIAS = 29135872ull;
constexpr size_t PO_DIR  = 29139968ull;
constexpr size_t PO_IDX  = 33334272ull;
constexpr size_t PO_FLAG = 33334400ull;
constexpr size_t FULL_NEED = P + 33334528ull;

constexpr int BO_T1 = 0, BO_T2 = 512, BO_M1 = 592, BO_M2 = 752, BO_M3 = 832;

// ---------------- dtype detect: bf16 vs f32 probe on text ----------------
__global__ void k_detect(const uint32_t* __restrict__ w, int* __restrict__ flag) {
  __shared__ int red[256];
  const int tid = threadIdx.x;
  int cnt = 0;
  for (int i = tid; i < 4096; i += 256) {
    uint32_t e = (w[i] >> 7) & 0xFFu;
    cnt += (e >= 119u && e <= 129u) ? 1 : 0;
  }
  red[tid] = cnt;
  __syncthreads();
  for (int s = 128; s > 0; s >>= 1) {
    if (tid < s) red[tid] += red[tid + s];
    __syncthreads();
  }
  if (tid == 0) *flag = (red[0] > 2048) ? 1 : 0;
}

// ---------------- flag-branched convert to f32 ----------------
__global__ void k_cvt(const void* __restrict__ in, float* __restrict__ out, int n,
                      const int* __restrict__ flag) {
  const int i = blockIdx.x * 256 + threadIdx.x;
  if (i >= n) return;
  if (*flag) {
    uint16_t u = ((const uint16_t*)in)[i];
    out[i] = __uint_as_float((uint32_t)u << 16);
  } else {
    out[i] = ((const float*)in)[i];
  }
}

// ---------------- weight transpose ----------------
__global__ void k_wtrans(const void* __restrict__ w, float* __restrict__ wT,
                         int CO, int CI, int KW, int total, const int* __restrict__ flag) {
  int id = blockIdx.x * 256 + threadIdx.x;
  if (id >= total) return;
  int co = id % CO;
  int rest = id / CO;
  int ci = rest % CI;
  int tap = rest / CI;
  int src = (co * CI + ci) * KW + tap;
  if (*flag) {
    uint16_t u = ((const uint16_t*)w)[src];
    wT[id] = __uint_as_float((uint32_t)u << 16);
  } else {
    wT[id] = ((const float*)w)[src];
  }
}

// ---------------- conv1d as implicit GEMM (pure f32) ----------------
template <int CIN, int KW, int COUT, int NTILE, int NR, int KC, int LOG2L, int ACT, bool MASK>
__global__ __launch_bounds__(256) void k_conv(const float* __restrict__ x,
                                              const float* __restrict__ wT,
                                              const float* __restrict__ bias,
                                              float* __restrict__ y,
                                              const int* __restrict__ lenArr) {
  constexpr int L = 1 << LOG2L;
  constexpr int PAD = (KW - 1) / 2;
  constexpr int MT = 128;
  constexpr int APAD = 132;
  constexpr int BPAD = NTILE + 4;
  __shared__ float As[KC][APAD];
  __shared__ float Bs[KC][BPAD];

  const int tid = threadIdx.x;
  const int tx = tid & 15;
  const int ty = tid >> 4;
  constexpr int NBLK = COUT / NTILE;
  const int m0 = (blockIdx.x / NBLK) * MT;
  const int n0 = (blockIdx.x % NBLK) * NTILE;

  float acc[8][NR];
#pragma unroll
  for (int i = 0; i < 8; ++i)
#pragma unroll
    for (int j = 0; j < NR; ++j) acc[i][j] = 0.f;

  for (int tap = 0; tap < KW; ++tap) {
    for (int k0 = 0; k0 < CIN; k0 += KC) {
      __syncthreads();
      constexpr int AF4 = MT * KC / 4;
      constexpr int F4R = KC / 4;
      for (int f = tid; f < AF4; f += 256) {
        int row = f / F4R;
        int ko = (f % F4R) * 4;
        int r = m0 + row;
        int b = r >> LOG2L;
        int pos = (r & (L - 1)) + tap - PAD;
        float4 v = make_float4(0.f, 0.f, 0.f, 0.f);
        if (pos >= 0 && pos < L)
          v = *reinterpret_cast<const float4*>(
              &x[((size_t)(b << LOG2L) + pos) * CIN + k0 + ko]);
        As[ko + 0][row] = v.x;
        As[ko + 1][row] = v.y;
        As[ko + 2][row] = v.z;
        As[ko + 3][row] = v.w;
      }
      constexpr int BF4 = KC * NTILE / 4;
      constexpr int BF4R = NTILE / 4;
      for (int f = tid; f < BF4; f += 256) {
        int kk = f / BF4R;
        int no = (f % BF4R) * 4;
        float4 v = *reinterpret_cast<const float4*>(
            &wT[((size_t)(tap * CIN + k0 + kk)) * COUT + n0 + no]);
        *reinterpret_cast<float4*>(&Bs[kk][no]) = v;
      }
      __syncthreads();
#pragma unroll 8
      for (int kk = 0; kk < KC; ++kk) {
        float4 a0 = *reinterpret_cast<const float4*>(&As[kk][ty * 8]);
        float4 a1 = *reinterpret_cast<const float4*>(&As[kk][ty * 8 + 4]);
        float av[8] = {a0.x, a0.y, a0.z, a0.w, a1.x, a1.y, a1.z, a1.w};
        float bv[NR];
#pragma unroll
        for (int j = 0; j < NR; ++j) bv[j] = Bs[kk][tx * NR + j];
#pragma unroll
        for (int i = 0; i < 8; ++i)
#pragma unroll
          for (int j = 0; j < NR; ++j) acc[i][j] = fmaf(av[i], bv[j], acc[i][j]);
      }
    }
  }
#pragma unroll
  for (int i = 0; i < 8; ++i) {
    int r = m0 + ty * 8 + i;
    int b = r >> LOG2L;
    int pos = r & (L - 1);
    bool zero = MASK && (pos >= lenArr[b]);
#pragma unroll
    for (int j = 0; j < NR; ++j) {
      int c = n0 + tx * NR + j;
      float v = acc[i][j] + bias[c];
      if (ACT == 1) v = fmaxf(v, 0.f);
      if (ACT == 2) v = (v >= 0.f) ? v : 0.01f * v;
      if (zero) v = 0.f;
      y[(size_t)r * COUT + c] = v;
    }
  }
}

// ---------------- row squared-norms ----------------
__global__ void k_norms(const float* __restrict__ e, float* __restrict__ out, int rows) {
  int tid = blockIdx.x * 256 + threadIdx.x;
  int row = tid >> 2, sub = tid & 3;
  if (row >= rows) return;
  const float* p = e + (size_t)row * DMEL;
  float s = 0.f;
#pragma unroll
  for (int j = 0; j < 5; ++j) {
    float4 v = *reinterpret_cast<const float4*>(&p[(sub + 4 * j) * 4]);
    s = fmaf(v.x, v.x, fmaf(v.y, v.y, fmaf(v.z, v.z, fmaf(v.w, v.w, s))));
  }
  s += __shfl_xor(s, 1);
  s += __shfl_xor(s, 2);
  if (sub == 0) out[row] = s;
}

// ---------------- softmax stats by recomputation ----------------
__global__ __launch_bounds__(256) void k_stats2(
    const float* __restrict__ te, const float* __restrict__ me,
    const float* __restrict__ na, const float* __restrict__ nb,
    const int* __restrict__ src_len, const int* __restrict__ mel_len,
    float* __restrict__ marr, float* __restrict__ rzarr) {
  const int b = blockIdx.x >> 5;
  const int t0 = (blockIdx.x & 31) << 6;
  __shared__ float Bt[DMEL][68];
  __shared__ float At[DMEL][68];
  __shared__ float redm[16][64];
  __shared__ float redz[16][64];
  const int tid = threadIdx.x;
  for (int f = tid; f < 64 * 20; f += 256) {
    int row = f / 20, ko = (f % 20) << 2;
    float4 v = *reinterpret_cast<const float4*>(
        &me[((size_t)b * NT_ + t0 + row) * DMEL + ko]);
    Bt[ko][row] = v.x; Bt[ko + 1][row] = v.y; Bt[ko + 2][row] = v.z; Bt[ko + 3][row] = v.w;
  }
  const int tx = tid & 15, sy = tid >> 4;
  const int sl = src_len[b], ml = mel_len[b];
  const float NEGINF = -__builtin_inff();
  float nbv[4], mACC[4], zACC[4];
#pragma unroll
  for (int j = 0; j < 4; ++j) {
    nbv[j] = nb[b * NT_ + t0 + (tx << 2) + j];
    mACC[j] = NEGINF;
    zACC[j] = 0.f;
  }
  for (int c = 0; c < 8; ++c) {
    const int s0 = c << 6;
    __syncthreads();
    for (int f = tid; f < 64 * 20; f += 256) {
      int row = f / 20, ko = (f % 20) << 2;
      float4 v = *reinterpret_cast<const float4*>(
          &te[((size_t)b * NS_ + s0 + row) * DMEL + ko]);
      At[ko][row] = v.x; At[ko + 1][row] = v.y; At[ko + 2][row] = v.z; At[ko + 3][row] = v.w;
    }
    __syncthreads();
    float acc[4][4];
#pragma unroll
    for (int i = 0; i < 4; ++i)
#pragma unroll
      for (int j = 0; j < 4; ++j) acc[i][j] = 0.f;
#pragma unroll 8
    for (int kk = 0; kk < DMEL; ++kk) {
      float4 a = *reinterpret_cast<const float4*>(&At[kk][sy << 2]);
      float4 bb = *reinterpret_cast<const float4*>(&Bt[kk][tx << 2]);
      float av[4] = {a.x, a.y, a.z, a.w}, bv[4] = {bb.x, bb.y, bb.z, bb.w};
#pragma unroll
      for (int i = 0; i < 4; ++i)
#pragma unroll
        for (int j = 0; j < 4; ++j) acc[i][j] = fmaf(av[i], bv[j], acc[i][j]);
    }
    float nav[4];
#pragma unroll
    for (int i = 0; i < 4; ++i) nav[i] = na[b * NS_ + s0 + (sy << 2) + i];
#pragma unroll
    for (int j = 0; j < 4; ++j) {
      const bool tvalid = (t0 + (tx << 2) + j) < ml;
      float ov[4];
      float mNew = mACC[j];
#pragma unroll
      for (int i = 0; i < 4; ++i) {
        float d2 = (nav[i] + nbv[j]) - 2.0f * acc[i][j];
        float dist = sqrtf(fmaxf(d2, 1e-12f));
        bool valid = ((s0 + (sy << 2) + i) < sl) && tvalid;
        ov[i] = valid ? -dist : -1e9f;
        mNew = fmaxf(mNew, ov[i]);
      }
      float scale = expf(mACC[j] - mNew);
      float zadd = 0.f;
#pragma unroll
      for (int i = 0; i < 4; ++i) zadd += expf(ov[i] - mNew);
      zACC[j] = zACC[j] * scale + zadd;
      mACC[j] = mNew;
    }
  }
#pragma unroll
  for (int j = 0; j < 4; ++j) {
    redm[sy][(tx << 2) + j] = mACC[j];
    redz[sy][(tx << 2) + j] = zACC[j];
  }
  __syncthreads();
  if (tid < 64) {
    float M = NEGINF, Z = 0.f;
#pragma unroll
    for (int y = 0; y < 16; ++y) {
      float m = redm[y][tid], z = redz[y][tid];
      float Mn = fmaxf(M, m);
      Z = Z * expf(M - Mn) + z * expf(m - Mn);
      M = Mn;
    }
    marr[b * NT_ + t0 + tid] = M;
    rzarr[b * NT_ + t0 + tid] = 1.0f / Z;
  }
}

// ---------------- finalize: soft/rev f32 out + f32 val for DP ----------------
__global__ __launch_bounds__(256) void k_final3(
    const float* __restrict__ te, const float* __restrict__ me,
    const float* __restrict__ na, const float* __restrict__ nb,
    const float* __restrict__ marr, const float* __restrict__ rzarr,
    const int* __restrict__ src_len, const int* __restrict__ mel_len,
    float* __restrict__ val,
    float* __restrict__ soft, float* __restrict__ rev) {
  const int idx = blockIdx.x;
  const int tt = idx & 31;
  const int st = (idx >> 5) & 7;
  const int b = idx >> 8;
  const int s0 = st << 6, t0 = tt << 6;
  __shared__ float At[DMEL][68];
  __shared__ float Bt[DMEL][68];
  __shared__ float pl[64][65];
  const int tid = threadIdx.x;
  for (int f = tid; f < 64 * 20; f += 256) {
    int row = f / 20, ko = (f % 20) << 2;
    float4 v = *reinterpret_cast<const float4*>(
        &te[((size_t)b * NS_ + s0 + row) * DMEL + ko]);
    At[ko][row] = v.x; At[ko + 1][row] = v.y; At[ko + 2][row] = v.z; At[ko + 3][row] = v.w;
  }
  for (int f = tid; f < 64 * 20; f += 256) {
    int row = f / 20, ko = (f % 20) << 2;
    float4 v = *reinterpret_cast<const float4*>(
        &me[((size_t)b * NT_ + t0 + row) * DMEL + ko]);
    Bt[ko][row] = v.x; Bt[ko + 1][row] = v.y; Bt[ko + 2][row] = v.z; Bt[ko + 3][row] = v.w;
  }
  __syncthreads();
  const int tx = tid & 15, sy = tid >> 4;
  float acc[4][4];
#pragma unroll
  for (int i = 0; i < 4; ++i)
#pragma unroll
    for (int j = 0; j < 4; ++j) acc[i][j] = 0.f;
#pragma unroll 8
  for (int kk = 0; kk < DMEL; ++kk) {
    float4 a = *reinterpret_cast<const float4*>(&At[kk][sy << 2]);
    float4 bb = *reinterpret_cast<const float4*>(&Bt[kk][tx << 2]);
    float av[4] = {a.x, a.y, a.z, a.w}, bv[4] = {bb.x, bb.y, bb.z, bb.w};
#pragma unroll
    for (int i = 0; i < 4; ++i)
#pragma unroll
      for (int j = 0; j < 4; ++j) acc[i][j] = fmaf(av[i], bv[j], acc[i][j]);
  }
  const int sl = src_len[b], ml = mel_len[b];
  float nav[4], nbv[4];
#pragma unroll
  for (int i = 0; i < 4; ++i) nav[i] = na[b * NS_ + s0 + (sy << 2) + i];
#pragma unroll
  for (int j = 0; j < 4; ++j) nbv[j] = nb[b * NT_ + t0 + (tx << 2) + j];
#pragma unroll
  for (int j = 0; j < 4; ++j) {
    const int t = t0 + (tx << 2) + j;
    const bool tvalid = t < ml;
    const float mv = marr[b * NT_ + t];
    const float rzv = rzarr[b * NT_ + t];
    float pv[4];
#pragma unroll
    for (int i = 0; i < 4; ++i) {
      float d2 = (nav[i] + nbv[j]) - 2.0f * acc[i][j];
      float dist = sqrtf(fmaxf(d2, 1e-12f));
      bool valid = ((s0 + (sy << 2) + i) < sl) && tvalid;
      float ov = valid ? -dist : -1e9f;
      float p = tvalid ? expf(ov - mv) * rzv : 0.f;
      pv[i] = p;
      pl[(tx << 2) + j][(sy << 2) + i] = p;
    }
    float4 o = make_float4(pv[0], pv[1], pv[2], pv[3]);
    *reinterpret_cast<float4*>(&val[((size_t)b * NT_ + t) * NS_ + s0 + (sy << 2)]) = o;
  }
  __syncthreads();
  const int lane = tid & 63, w = tid >> 6;
#pragma unroll 4
  for (int i = 0; i < 16; ++i) {
    const int s_loc = (w << 4) + i;
    const int s = s0 + s_loc;
    float p = pl[lane][s_loc];
    size_t o = ((size_t)b * NS_ + s) * NT_ + t0 + lane;
    soft[o] = p;
    bool r = (s >= sl) || ((t0 + lane) >= ml);
    rev[o] = r ? 1.0f : 0.0f;
  }
}

// ---------------- async global->LDS 16B helper ----------------
__device__ __forceinline__ void dp_issue16(const float* g, float* l) {
  __builtin_amdgcn_global_load_lds(
      (const __attribute__((address_space(1))) void*)g,
      (__attribute__((address_space(3))) void*)l, 16, 0, 0);
}

// lane i <- lane i-1 via DPP wave_shr:1 (VALU, no LDS pipe). Lane 0 -> 0.
__device__ __forceinline__ float dp_shr1(float x) {
  int r = __builtin_amdgcn_update_dpp(0, __float_as_int(x), 0x138, 0xF, 0xF, true);
  return __int_as_float(r);
}

// ---------------- DP forward scan: 1 consumer + 4 producer waves ----------------
// LDS per row de-interleaved (rule 21): [0..255]=even 16B chunks, [256..511]=odd.
// Consumer boundary shuffle via DPP wave_shr:1 (not ds_bpermute) - keeps the
// inter-row serial chain off the LDS pipe (~120cyc -> ~8cyc).
__global__ __launch_bounds__(320) void k_dp(const float* __restrict__ val,
                                            const int* __restrict__ src_len,
                                            const int* __restrict__ mel_len,
                                            uint32_t* __restrict__ dir) {
  __shared__ float buf[2][16][512];  // 64 KB double buffer
  const int b = blockIdx.x;
  const int wv = threadIdx.x >> 6;   // 0 = consumer, 1..4 = producers
  const int lane = threadIdx.x & 63;
  const float* base = val + (size_t)b * NT_ * NS_;
  const int sl = src_len[b];
  const int ml = mel_len[b];
  const float NEGINF = -__builtin_inff();

  float v[8];
#pragma unroll
  for (int j = 0; j < 8; ++j) v[j] = 0.0f;
  uint32_t bw[8];
#pragma unroll
  for (int j = 0; j < 8; ++j) bw[j] = 0u;

  // prologue: producers stage chunk 0 (4 rows each)
  if (wv > 0) {
#pragma unroll
    for (int rr = 0; rr < 4; ++rr) {
      const int r = ((wv - 1) << 2) + rr;
      const float* g = base + (size_t)r * NS_ + (lane << 3);
      dp_issue16(g, &buf[0][r][0]);        // even chunks -> first half
      dp_issue16(g + 4, &buf[0][r][256]);  // odd chunks  -> second half
    }
    asm volatile("s_waitcnt vmcnt(0)" ::: "memory");
  }
  __syncthreads();

  for (int c = 0; c < 128; ++c) {
    if (wv > 0) {
      // producers: stage chunk c+1 into the other buffer, drain own vmcnt
      if (c + 1 < 128) {
        const int pb = (c + 1) & 1;
        const float* cb = base + (size_t)(c + 1) * 16 * NS_;
#pragma unroll
        for (int rr = 0; rr < 4; ++rr) {
          const int r = ((wv - 1) << 2) + rr;
          const float* g = cb + (size_t)r * NS_ + (lane << 3);
          dp_issue16(g, &buf[pb][r][0]);
          dp_issue16(g + 4, &buf[pb][r][256]);
        }
      }
      asm volatile("s_waitcnt vmcnt(0)" ::: "memory");
    } else {
      // consumer: compute 16 rows of chunk c (4-row register batches)
      const float* rowbase = &buf[c & 1][0][0];
      const int tbase = c << 4;
#pragma unroll
      for (int rb = 0; rb < 4; ++rb) {
        float4 d0[4], d1[4];
#pragma unroll
        for (int rr = 0; rr < 4; ++rr) {
          const float* rp = rowbase + (((rb << 2) + rr) << 9);
          d0[rr] = *reinterpret_cast<const float4*>(rp + (lane << 2));
          d1[rr] = *reinterpret_cast<const float4*>(rp + 256 + (lane << 2));
        }
#pragma unroll
        for (int rr = 0; rr < 4; ++rr) {
          const int t = tbase + (rb << 2) + rr;
          float cc[8] = {d0[rr].x, d0[rr].y, d0[rr].z, d0[rr].w,
                         d1[rr].x, d1[rr].y, d1[rr].z, d1[rr].w};
          float up = dp_shr1(v[7]);
          float prev = (lane == 0) ? NEGINF : up;
          const bool tml = t < ml;
          const int sh = t & 31;
#pragma unroll
          for (int j = 0; j < 8; ++j) {
            float cur = v[j];
            bool keep = cur >= prev;
            float vm = keep ? cur : prev;
            int s = (lane << 3) + j;
            float vn = (s <= t) ? vm + cc[j] : NEGINF;
            bool bit = (tml && (s < sl)) ? keep : true;
            bw[j] |= (uint32_t)bit << sh;
            v[j] = vn;
            prev = cur;
          }
        }
      }
      if (c & 1) {  // 32 rows accumulated -> store direction words
        const int c32 = c >> 1;
#pragma unroll
        for (int j = 0; j < 8; ++j) {
          dir[((size_t)(b * NS_) + (lane << 3) + j) * 64 + c32] = bw[j];
          bw[j] = 0u;
        }
      }
    }
    __syncthreads();
  }
}

// ---------------- backtrack (two half-T phases) ----------------
__global__ __launch_bounds__(256) void k_backtrack(
    const uint32_t* __restrict__ dir, const int* __restrict__ src_len,
    const int* __restrict__ mel_len, float* __restrict__ hard,
    int* __restrict__ idxio, int phase) {
  __shared__ uint32_t dl[NS_ * 32];
  const int b = blockIdx.x, tid = threadIdx.x;
  const uint32_t* db = dir + (size_t)b * NS_ * 64;
  const int woff = phase ? 0 : 32;
  for (int f = tid; f < 4096; f += 256) {
    int s = f >> 3;
    int wo = (f & 7) << 2;
    *reinterpret_cast<uint4*>(&dl[s * 32 + wo]) =
        *reinterpret_cast<const uint4*>(&db[s * 64 + woff + wo]);
  }
  __syncthreads();
  if (tid == 0) {
    const int ml = mel_len[b];
    int idx = phase ? idxio[b] : (src_len[b] - 1);
    if (idx < 0) idx = 0;
    if (idx > NS_ - 1) idx = NS_ - 1;
    const int thi = phase ? 1023 : 2047;
    const int tlo = phase ? 0 : 1024;
    int cw = -1, ci = -1;
    uint32_t w = 0;
    for (int t = thi; t >= tlo; --t) {
      int wi = t >> 5;
      if (wi != cw || idx != ci) {
        w = dl[idx * 32 + (wi - woff)];
        cw = wi;
        ci = idx;
      }
      if (t < ml) hard[((size_t)(b * NS_) + idx) * NT_ + t] = 1.0f;
      int step = (int)((w >> (t & 31)) & 1) - 1;
      idx += step;
      if (idx < 0) idx = 0;
    }
    if (!phase) idxio[b] = idx;
  }
}

// ---------------- host launch ----------------
extern "C" void kernel_launch(void* const* d_in, const int* in_sizes, int n_in,
                              void* d_out, int out_size, void* d_ws, size_t ws_size,
                              hipStream_t stream) {
  if (n_in != 17) return;
  if (ws_size < FULL_NEED) return;

  const void* text = d_in[0];
  const void* mel = d_in[1];
  const int* src_len = (const int*)d_in[2];
  const int* mel_len = (const int*)d_in[3];
  const void* tw1 = d_in[7];
  const void* tb1 = d_in[8];
  const void* tw2 = d_in[9];
  const void* tb2 = d_in[10];
  const void* mw1 = d_in[11];
  const void* mb1 = d_in[12];
  const void* mw2 = d_in[13];
  const void* mb2 = d_in[14];
  const void* mw3 = d_in[15];
  const void* mb3 = d_in[16];

  char* w8 = (char*)d_ws;
  float* mel_f32 = (float*)(w8 + 0);
  float* melh1 = (float*)(w8 + 20971520ull);
  float* mh2 = (float*)(w8 + 62914560ull);
  float* text_f32 = (float*)(w8 + 83886080ull);
  float* texth1 = (float*)(w8 + 100663296ull);
  float* val = (float*)(w8 + 0);

  float* te = (float*)(w8 + P + PO_TE);
  float* me = (float*)(w8 + P + PO_ME);
  float* na = (float*)(w8 + P + PO_NA);
  float* nb = (float*)(w8 + P + PO_NB);
  float* marr = (float*)(w8 + P + PO_M);
  float* rzarr = (float*)(w8 + P + PO_RZ);
  float* wt1 = (float*)(w8 + P + PO_W1);
  float* wt2 = (float*)(w8 + P + PO_W2);
  float* wt3 = (float*)(w8 + P + PO_W3);
  float* wt4 = (float*)(w8 + P + PO_W4);
  float* wt5 = (float*)(w8 + P + PO_W5);
  float* biasb = (float*)(w8 + P + PO_BIAS);
  uint32_t* dir = (uint32_t*)(w8 + P + PO_DIR);
  int* idxio = (int*)(w8 + P + PO_IDX);
  int* flag = (int*)(w8 + P + PO_FLAG);

  // outputs are float32
  float* soft = (float*)d_out;
  float* hard = soft + (size_t)NB_ * NS_ * NT_;
  float* rev = soft + 2 * (size_t)NB_ * NS_ * NT_;

  // dtype detect + converts
  k_detect<<<1, 256, 0, stream>>>((const uint32_t*)text, flag);
  k_cvt<<<(NB_ * NS_ * 256 + 255) / 256, 256, 0, stream>>>(text, text_f32, NB_ * NS_ * 256, flag);
  k_cvt<<<(NB_ * NT_ * 80 + 255) / 256, 256, 0, stream>>>(mel, mel_f32, NB_ * NT_ * 80, flag);
  k_cvt<<<2, 256, 0, stream>>>(tb1, biasb + BO_T1, 512, flag);
  k_cvt<<<1, 256, 0, stream>>>(tb2, biasb + BO_T2, 80, flag);
  k_cvt<<<1, 256, 0, stream>>>(mb1, biasb + BO_M1, 160, flag);
  k_cvt<<<1, 256, 0, stream>>>(mb2, biasb + BO_M2, 80, flag);
  k_cvt<<<1, 256, 0, stream>>>(mb3, biasb + BO_M3, 80, flag);

  // weight transposes
  k_wtrans<<<(512 * 256 * 3 + 255) / 256, 256, 0, stream>>>(tw1, wt1, 512, 256, 3, 512 * 256 * 3, flag);
  k_wtrans<<<(80 * 512 + 255) / 256, 256, 0, stream>>>(tw2, wt2, 80, 512, 1, 80 * 512, flag);
  k_wtrans<<<(160 * 80 * 3 + 255) / 256, 256, 0, stream>>>(mw1, wt3, 160, 80, 3, 160 * 80 * 3, flag);
  k_wtrans<<<(80 * 160 * 3 + 255) / 256, 256, 0, stream>>>(mw2, wt4, 80, 160, 3, 80 * 160 * 3, flag);
  k_wtrans<<<(80 * 80 + 255) / 256, 256, 0, stream>>>(mw3, wt5, 80, 80, 1, 80 * 80, flag);

  // encoders (pure f32)
  k_conv<80, 3, 160, 80, 5, 16, 11, 2, false><<<512 * 2, 256, 0, stream>>>(mel_f32, wt3, biasb + BO_M1, melh1, nullptr);
  k_conv<160, 3, 80, 80, 5, 32, 11, 2, false><<<512 * 1, 256, 0, stream>>>(melh1, wt4, biasb + BO_M2, mh2, nullptr);
  k_conv<80, 1, 80, 80, 5, 16, 11, 0, true><<<512 * 1, 256, 0, stream>>>(mh2, wt5, biasb + BO_M3, me, mel_len);
  k_conv<256, 3, 512, 64, 4, 32, 9, 1, false><<<128 * 8, 256, 0, stream>>>(text_f32, wt1, biasb + BO_T1, texth1, nullptr);
  k_conv<512, 1, 80, 80, 5, 32, 9, 0, true><<<128 * 1, 256, 0, stream>>>(texth1, wt2, biasb + BO_T2, te, src_len);

  // norms
  k_norms<<<(NB_ * NS_ * 4) / 256, 256, 0, stream>>>(te, na, NB_ * NS_);
  k_norms<<<(NB_ * NT_ * 4) / 256, 256, 0, stream>>>(me, nb, NB_ * NT_);

  // softmax stats + finalize
  k_stats2<<<NB_ * 32, 256, 0, stream>>>(te, me, na, nb, src_len, mel_len, marr, rzarr);
  k_final3<<<NB_ * 8 * 32, 256, 0, stream>>>(te, me, na, nb, marr, rzarr, src_len, mel_len,
                                             val, soft, rev);

  // hard_A
  hipMemsetAsync(hard, 0, (size_t)NB_ * NS_ * NT_ * 4, stream);
  k_dp<<<NB_, 320, 0, stream>>>(val, src_len, mel_len, dir);
  k_backtrack<<<NB_, 256, 0, stream>>>(dir, src_len, mel_len, hard, idxio, 0);
  k_backtrack<<<NB_, 256, 0, stream>>>(dir, src_len, mel_len, hard, idxio, 1);
}

// Round 10
// 1349.555 us; speedup vs baseline: 1.0758x; 1.0433x over previous
//
#include <hip/hip_runtime.h>
#include <hip/hip_bf16.h>
#include <cstdint>

// Problem constants
constexpr int NB_ = 32;     // batch
constexpr int NS_ = 512;    // text length S
constexpr int NT_ = 2048;   // mel length T
constexpr int DMEL = 80;    // embedding dim

// ---------------- workspace layout ----------------
constexpr size_t P = 134217728ull;  // persistent block base
constexpr size_t PO_TE   = 0ull;
constexpr size_t PO_ME   = 5242880ull;
constexpr size_t PO_NA   = 26214400ull;
constexpr size_t PO_NB   = 26279936ull;
constexpr size_t PO_M    = 26542080ull;
constexpr size_t PO_RZ   = 26804224ull;
constexpr size_t PO_W1   = 27066368ull;
constexpr size_t PO_W2   = 28639232ull;
constexpr size_t PO_W3   = 28803072ull;
constexpr size_t PO_W4   = 28956672ull;
constexpr size_t PO_W5   = 29110272ull;
constexpr size_t PO_BIAS = 29135872ull;
constexpr size_t PO_DIR  = 29139968ull;
constexpr size_t PO_IDX  = 33334272ull;
constexpr size_t PO_FLAG = 33334400ull;
constexpr size_t FULL_NEED = P + 33334528ull;

constexpr int BO_T1 = 0, BO_T2 = 512, BO_M1 = 592, BO_M2 = 752, BO_M3 = 832;

// ---------------- dtype detect: bf16 vs f32 probe on text ----------------
__global__ void k_detect(const uint32_t* __restrict__ w, int* __restrict__ flag) {
  __shared__ int red[256];
  const int tid = threadIdx.x;
  int cnt = 0;
  for (int i = tid; i < 4096; i += 256) {
    uint32_t e = (w[i] >> 7) & 0xFFu;
    cnt += (e >= 119u && e <= 129u) ? 1 : 0;
  }
  red[tid] = cnt;
  __syncthreads();
  for (int s = 128; s > 0; s >>= 1) {
    if (tid < s) red[tid] += red[tid + s];
    __syncthreads();
  }
  if (tid == 0) *flag = (red[0] > 2048) ? 1 : 0;
}

// ---------------- flag-branched convert to f32 ----------------
__global__ void k_cvt(const void* __restrict__ in, float* __restrict__ out, int n,
                      const int* __restrict__ flag) {
  const int i = blockIdx.x * 256 + threadIdx.x;
  if (i >= n) return;
  if (*flag) {
    uint16_t u = ((const uint16_t*)in)[i];
    out[i] = __uint_as_float((uint32_t)u << 16);
  } else {
    out[i] = ((const float*)in)[i];
  }
}

// ---------------- weight transpose ----------------
__global__ void k_wtrans(const void* __restrict__ w, float* __restrict__ wT,
                         int CO, int CI, int KW, int total, const int* __restrict__ flag) {
  int id = blockIdx.x * 256 + threadIdx.x;
  if (id >= total) return;
  int co = id % CO;
  int rest = id / CO;
  int ci = rest % CI;
  int tap = rest / CI;
  int src = (co * CI + ci) * KW + tap;
  if (*flag) {
    uint16_t u = ((const uint16_t*)w)[src];
    wT[id] = __uint_as_float((uint32_t)u << 16);
  } else {
    wT[id] = ((const float*)w)[src];
  }
}

// ---------------- conv1d as implicit GEMM (pure f32) ----------------
template <int CIN, int KW, int COUT, int NTILE, int NR, int KC, int LOG2L, int ACT, bool MASK>
__global__ __launch_bounds__(256) void k_conv(const float* __restrict__ x,
                                              const float* __restrict__ wT,
                                              const float* __restrict__ bias,
                                              float* __restrict__ y,
                                              const int* __restrict__ lenArr) {
  constexpr int L = 1 << LOG2L;
  constexpr int PAD = (KW - 1) / 2;
  constexpr int MT = 128;
  constexpr int APAD = 132;
  constexpr int BPAD = NTILE + 4;
  __shared__ float As[KC][APAD];
  __shared__ float Bs[KC][BPAD];

  const int tid = threadIdx.x;
  const int tx = tid & 15;
  const int ty = tid >> 4;
  constexpr int NBLK = COUT / NTILE;
  const int m0 = (blockIdx.x / NBLK) * MT;
  const int n0 = (blockIdx.x % NBLK) * NTILE;

  float acc[8][NR];
#pragma unroll
  for (int i = 0; i < 8; ++i)
#pragma unroll
    for (int j = 0; j < NR; ++j) acc[i][j] = 0.f;

  for (int tap = 0; tap < KW; ++tap) {
    for (int k0 = 0; k0 < CIN; k0 += KC) {
      __syncthreads();
      constexpr int AF4 = MT * KC / 4;
      constexpr int F4R = KC / 4;
      for (int f = tid; f < AF4; f += 256) {
        int row = f / F4R;
        int ko = (f % F4R) * 4;
        int r = m0 + row;
        int b = r >> LOG2L;
        int pos = (r & (L - 1)) + tap - PAD;
        float4 v = make_float4(0.f, 0.f, 0.f, 0.f);
        if (pos >= 0 && pos < L)
          v = *reinterpret_cast<const float4*>(
              &x[((size_t)(b << LOG2L) + pos) * CIN + k0 + ko]);
        As[ko + 0][row] = v.x;
        As[ko + 1][row] = v.y;
        As[ko + 2][row] = v.z;
        As[ko + 3][row] = v.w;
      }
      constexpr int BF4 = KC * NTILE / 4;
      constexpr int BF4R = NTILE / 4;
      for (int f = tid; f < BF4; f += 256) {
        int kk = f / BF4R;
        int no = (f % BF4R) * 4;
        float4 v = *reinterpret_cast<const float4*>(
            &wT[((size_t)(tap * CIN + k0 + kk)) * COUT + n0 + no]);
        *reinterpret_cast<float4*>(&Bs[kk][no]) = v;
      }
      __syncthreads();
#pragma unroll 8
      for (int kk = 0; kk < KC; ++kk) {
        float4 a0 = *reinterpret_cast<const float4*>(&As[kk][ty * 8]);
        float4 a1 = *reinterpret_cast<const float4*>(&As[kk][ty * 8 + 4]);
        float av[8] = {a0.x, a0.y, a0.z, a0.w, a1.x, a1.y, a1.z, a1.w};
        float bv[NR];
#pragma unroll
        for (int j = 0; j < NR; ++j) bv[j] = Bs[kk][tx * NR + j];
#pragma unroll
        for (int i = 0; i < 8; ++i)
#pragma unroll
          for (int j = 0; j < NR; ++j) acc[i][j] = fmaf(av[i], bv[j], acc[i][j]);
      }
    }
  }
#pragma unroll
  for (int i = 0; i < 8; ++i) {
    int r = m0 + ty * 8 + i;
    int b = r >> LOG2L;
    int pos = r & (L - 1);
    bool zero = MASK && (pos >= lenArr[b]);
#pragma unroll
    for (int j = 0; j < NR; ++j) {
      int c = n0 + tx * NR + j;
      float v = acc[i][j] + bias[c];
      if (ACT == 1) v = fmaxf(v, 0.f);
      if (ACT == 2) v = (v >= 0.f) ? v : 0.01f * v;
      if (zero) v = 0.f;
      y[(size_t)r * COUT + c] = v;
    }
  }
}

// ---------------- row squared-norms ----------------
__global__ void k_norms(const float* __restrict__ e, float* __restrict__ out, int rows) {
  int tid = blockIdx.x * 256 + threadIdx.x;
  int row = tid >> 2, sub = tid & 3;
  if (row >= rows) return;
  const float* p = e + (size_t)row * DMEL;
  float s = 0.f;
#pragma unroll
  for (int j = 0; j < 5; ++j) {
    float4 v = *reinterpret_cast<const float4*>(&p[(sub + 4 * j) * 4]);
    s = fmaf(v.x, v.x, fmaf(v.y, v.y, fmaf(v.z, v.z, fmaf(v.w, v.w, s))));
  }
  s += __shfl_xor(s, 1);
  s += __shfl_xor(s, 2);
  if (sub == 0) out[row] = s;
}

// ---------------- softmax stats by recomputation ----------------
__global__ __launch_bounds__(256) void k_stats2(
    const float* __restrict__ te, const float* __restrict__ me,
    const float* __restrict__ na, const float* __restrict__ nb,
    const int* __restrict__ src_len, const int* __restrict__ mel_len,
    float* __restrict__ marr, float* __restrict__ rzarr) {
  const int b = blockIdx.x >> 5;
  const int t0 = (blockIdx.x & 31) << 6;
  __shared__ float Bt[DMEL][68];
  __shared__ float At[DMEL][68];
  __shared__ float redm[16][64];
  __shared__ float redz[16][64];
  const int tid = threadIdx.x;
  for (int f = tid; f < 64 * 20; f += 256) {
    int row = f / 20, ko = (f % 20) << 2;
    float4 v = *reinterpret_cast<const float4*>(
        &me[((size_t)b * NT_ + t0 + row) * DMEL + ko]);
    Bt[ko][row] = v.x; Bt[ko + 1][row] = v.y; Bt[ko + 2][row] = v.z; Bt[ko + 3][row] = v.w;
  }
  const int tx = tid & 15, sy = tid >> 4;
  const int sl = src_len[b], ml = mel_len[b];
  const float NEGINF = -__builtin_inff();
  float nbv[4], mACC[4], zACC[4];
#pragma unroll
  for (int j = 0; j < 4; ++j) {
    nbv[j] = nb[b * NT_ + t0 + (tx << 2) + j];
    mACC[j] = NEGINF;
    zACC[j] = 0.f;
  }
  for (int c = 0; c < 8; ++c) {
    const int s0 = c << 6;
    __syncthreads();
    for (int f = tid; f < 64 * 20; f += 256) {
      int row = f / 20, ko = (f % 20) << 2;
      float4 v = *reinterpret_cast<const float4*>(
          &te[((size_t)b * NS_ + s0 + row) * DMEL + ko]);
      At[ko][row] = v.x; At[ko + 1][row] = v.y; At[ko + 2][row] = v.z; At[ko + 3][row] = v.w;
    }
    __syncthreads();
    float acc[4][4];
#pragma unroll
    for (int i = 0; i < 4; ++i)
#pragma unroll
      for (int j = 0; j < 4; ++j) acc[i][j] = 0.f;
#pragma unroll 8
    for (int kk = 0; kk < DMEL; ++kk) {
      float4 a = *reinterpret_cast<const float4*>(&At[kk][sy << 2]);
      float4 bb = *reinterpret_cast<const float4*>(&Bt[kk][tx << 2]);
      float av[4] = {a.x, a.y, a.z, a.w}, bv[4] = {bb.x, bb.y, bb.z, bb.w};
#pragma unroll
      for (int i = 0; i < 4; ++i)
#pragma unroll
        for (int j = 0; j < 4; ++j) acc[i][j] = fmaf(av[i], bv[j], acc[i][j]);
    }
    float nav[4];
#pragma unroll
    for (int i = 0; i < 4; ++i) nav[i] = na[b * NS_ + s0 + (sy << 2) + i];
#pragma unroll
    for (int j = 0; j < 4; ++j) {
      const bool tvalid = (t0 + (tx << 2) + j) < ml;
      float ov[4];
      float mNew = mACC[j];
#pragma unroll
      for (int i = 0; i < 4; ++i) {
        float d2 = (nav[i] + nbv[j]) - 2.0f * acc[i][j];
        float dist = sqrtf(fmaxf(d2, 1e-12f));
        bool valid = ((s0 + (sy << 2) + i) < sl) && tvalid;
        ov[i] = valid ? -dist : -1e9f;
        mNew = fmaxf(mNew, ov[i]);
      }
      float scale = expf(mACC[j] - mNew);
      float zadd = 0.f;
#pragma unroll
      for (int i = 0; i < 4; ++i) zadd += expf(ov[i] - mNew);
      zACC[j] = zACC[j] * scale + zadd;
      mACC[j] = mNew;
    }
  }
#pragma unroll
  for (int j = 0; j < 4; ++j) {
    redm[sy][(tx << 2) + j] = mACC[j];
    redz[sy][(tx << 2) + j] = zACC[j];
  }
  __syncthreads();
  if (tid < 64) {
    float M = NEGINF, Z = 0.f;
#pragma unroll
    for (int y = 0; y < 16; ++y) {
      float m = redm[y][tid], z = redz[y][tid];
      float Mn = fmaxf(M, m);
      Z = Z * expf(M - Mn) + z * expf(m - Mn);
      M = Mn;
    }
    marr[b * NT_ + t0 + tid] = M;
    rzarr[b * NT_ + t0 + tid] = 1.0f / Z;
  }
}

// ---------------- finalize: soft/rev f32 out + f32 val for DP ----------------
__global__ __launch_bounds__(256) void k_final3(
    const float* __restrict__ te, const float* __restrict__ me,
    const float* __restrict__ na, const float* __restrict__ nb,
    const float* __restrict__ marr, const float* __restrict__ rzarr,
    const int* __restrict__ src_len, const int* __restrict__ mel_len,
    float* __restrict__ val,
    float* __restrict__ soft, float* __restrict__ rev) {
  const int idx = blockIdx.x;
  const int tt = idx & 31;
  const int st = (idx >> 5) & 7;
  const int b = idx >> 8;
  const int s0 = st << 6, t0 = tt << 6;
  __shared__ float At[DMEL][68];
  __shared__ float Bt[DMEL][68];
  __shared__ float pl[64][65];
  const int tid = threadIdx.x;
  for (int f = tid; f < 64 * 20; f += 256) {
    int row = f / 20, ko = (f % 20) << 2;
    float4 v = *reinterpret_cast<const float4*>(
        &te[((size_t)b * NS_ + s0 + row) * DMEL + ko]);
    At[ko][row] = v.x; At[ko + 1][row] = v.y; At[ko + 2][row] = v.z; At[ko + 3][row] = v.w;
  }
  for (int f = tid; f < 64 * 20; f += 256) {
    int row = f / 20, ko = (f % 20) << 2;
    float4 v = *reinterpret_cast<const float4*>(
        &me[((size_t)b * NT_ + t0 + row) * DMEL + ko]);
    Bt[ko][row] = v.x; Bt[ko + 1][row] = v.y; Bt[ko + 2][row] = v.z; Bt[ko + 3][row] = v.w;
  }
  __syncthreads();
  const int tx = tid & 15, sy = tid >> 4;
  float acc[4][4];
#pragma unroll
  for (int i = 0; i < 4; ++i)
#pragma unroll
    for (int j = 0; j < 4; ++j) acc[i][j] = 0.f;
#pragma unroll 8
  for (int kk = 0; kk < DMEL; ++kk) {
    float4 a = *reinterpret_cast<const float4*>(&At[kk][sy << 2]);
    float4 bb = *reinterpret_cast<const float4*>(&Bt[kk][tx << 2]);
    float av[4] = {a.x, a.y, a.z, a.w}, bv[4] = {bb.x, bb.y, bb.z, bb.w};
#pragma unroll
    for (int i = 0; i < 4; ++i)
#pragma unroll
      for (int j = 0; j < 4; ++j) acc[i][j] = fmaf(av[i], bv[j], acc[i][j]);
  }
  const int sl = src_len[b], ml = mel_len[b];
  float nav[4], nbv[4];
#pragma unroll
  for (int i = 0; i < 4; ++i) nav[i] = na[b * NS_ + s0 + (sy << 2) + i];
#pragma unroll
  for (int j = 0; j < 4; ++j) nbv[j] = nb[b * NT_ + t0 + (tx << 2) + j];
#pragma unroll
  for (int j = 0; j < 4; ++j) {
    const int t = t0 + (tx << 2) + j;
    const bool tvalid = t < ml;
    const float mv = marr[b * NT_ + t];
    const float rzv = rzarr[b * NT_ + t];
    float pv[4];
#pragma unroll
    for (int i = 0; i < 4; ++i) {
      float d2 = (nav[i] + nbv[j]) - 2.0f * acc[i][j];
      float dist = sqrtf(fmaxf(d2, 1e-12f));
      bool valid = ((s0 + (sy << 2) + i) < sl) && tvalid;
      float ov = valid ? -dist : -1e9f;
      float p = tvalid ? expf(ov - mv) * rzv : 0.f;
      pv[i] = p;
      pl[(tx << 2) + j][(sy << 2) + i] = p;
    }
    float4 o = make_float4(pv[0], pv[1], pv[2], pv[3]);
    *reinterpret_cast<float4*>(&val[((size_t)b * NT_ + t) * NS_ + s0 + (sy << 2)]) = o;
  }
  __syncthreads();
  const int lane = tid & 63, w = tid >> 6;
#pragma unroll 4
  for (int i = 0; i < 16; ++i) {
    const int s_loc = (w << 4) + i;
    const int s = s0 + s_loc;
    float p = pl[lane][s_loc];
    size_t o = ((size_t)b * NS_ + s) * NT_ + t0 + lane;
    soft[o] = p;
    bool r = (s >= sl) || ((t0 + lane) >= ml);
    rev[o] = r ? 1.0f : 0.0f;
  }
}

// lane i <- lane i-1 via DPP wave_shr:1 (VALU, no LDS pipe). Lane 0 -> 0.
__device__ __forceinline__ float dp_shr1(float x) {
  int r = __builtin_amdgcn_update_dpp(0, __float_as_int(x), 0x138, 0xF, 0xF, true);
  return __int_as_float(r);
}

// Consumer chunk body: 16 rows, 4-row register batches. MASKED = apply (s<=t).
#define DP_CHUNK(MASKED)                                                      \
  _Pragma("unroll")                                                           \
  for (int rb8 = 0; rb8 < 4; ++rb8) {                                         \
    float4 d0[4], d1[4];                                                      \
    _Pragma("unroll")                                                         \
    for (int rr = 0; rr < 4; ++rr) {                                          \
      const float* rp = rowbase + (((rb8 << 2) + rr) << 9);                   \
      d0[rr] = *reinterpret_cast<const float4*>(rp + (lane << 2));            \
      d1[rr] = *reinterpret_cast<const float4*>(rp + 256 + (lane << 2));      \
    }                                                                         \
    _Pragma("unroll")                                                         \
    for (int rr = 0; rr < 4; ++rr) {                                          \
      const int t = tbase + (rb8 << 2) + rr;                                  \
      float cc[8] = {d0[rr].x, d0[rr].y, d0[rr].z, d0[rr].w,                  \
                     d1[rr].x, d1[rr].y, d1[rr].z, d1[rr].w};                 \
      const int sh = t & 31;                                                  \
      if (t < ml) {                                                           \
        float up = dp_shr1(v[7]);                                             \
        float prev = (lane == 0) ? NEGINF : up;                               \
        _Pragma("unroll")                                                     \
        for (int j = 0; j < 8; ++j) {                                         \
          float cur = v[j];                                                   \
          bool keep = cur >= prev;                                            \
          float vm = fmaxf(cur, prev);                                        \
          float vn;                                                           \
          if (MASKED) {                                                       \
            int s = (lane << 3) + j;                                          \
            vn = (s <= t) ? vm + cc[j] : NEGINF;                              \
          } else {                                                            \
            vn = vm + cc[j];                                                  \
          }                                                                   \
          uint32_t bit = keep ? 1u : inv[j];                                  \
          bw[j] |= bit << sh;                                                 \
          v[j] = vn;                                                          \
          prev = cur;                                                         \
        }                                                                     \
      } else {                                                                \
        _Pragma("unroll")                                                     \
        for (int j = 0; j < 8; ++j) bw[j] |= 1u << sh;                        \
      }                                                                       \
    }                                                                         \
  }

// ---------------- DP forward scan: 1 consumer + 2 reg-staging producer waves ----
// Producers: contiguous global_load_dwordx4 (coalesced) -> regs -> ds_write_b128
// into de-interleaved row layout ([0..255]=even 16B groups, [256..511]=odd).
// Loads for chunk c+2 issued at iter c, written at iter c+1 (full-iteration
// latency slack, T14). Consumer reads are linear b128 = conflict-free; boundary
// shuffle via DPP. Rows t>=ml short-circuit to all-1 direction bits.
__global__ __launch_bounds__(192) void k_dp(const float* __restrict__ val,
                                            const int* __restrict__ src_len,
                                            const int* __restrict__ mel_len,
                                            uint32_t* __restrict__ dir) {
  __shared__ float buf[2][16][512];  // 64 KB double buffer
  const int b = blockIdx.x;
  const int wv = threadIdx.x >> 6;   // 0 = consumer, 1..2 = producers
  const int lane = threadIdx.x & 63;
  const float* base = val + (size_t)b * NT_ * NS_;
  const int sl = src_len[b];
  const int ml = mel_len[b];
  const float NEGINF = -__builtin_inff();

  // producer state: 8 rows per producer wave, de-interleave write positions
  float4 ra[8], rb[8];
  const int r0 = (wv - 1) << 3;
  const int g2 = 64 + lane;
  const int pA = (lane & 1) ? 64 + (lane >> 1) : (lane >> 1);
  const int pB = (g2 & 1) ? 64 + (g2 >> 1) : (g2 >> 1);

  // consumer state
  float v[8];
  uint32_t bw[8], inv[8];
#pragma unroll
  for (int j = 0; j < 8; ++j) {
    v[j] = 0.0f;
    bw[j] = 0u;
    int s = (lane << 3) + j;
    inv[j] = (s < sl) ? 0u : 1u;
  }

  if (wv > 0) {
    // stage chunk 0 into buf0; preload chunk 1 into regs
#pragma unroll
    for (int rr = 0; rr < 8; ++rr) {
      const float* g = base + (size_t)(r0 + rr) * NS_;
      ra[rr] = *reinterpret_cast<const float4*>(g + (lane << 2));
      rb[rr] = *reinterpret_cast<const float4*>(g + 256 + (lane << 2));
    }
#pragma unroll
    for (int rr = 0; rr < 8; ++rr) {
      float* l = &buf[0][r0 + rr][0];
      *reinterpret_cast<float4*>(l + (pA << 2)) = ra[rr];
      *reinterpret_cast<float4*>(l + (pB << 2)) = rb[rr];
    }
#pragma unroll
    for (int rr = 0; rr < 8; ++rr) {
      const float* g = base + (size_t)(16 + r0 + rr) * NS_;
      ra[rr] = *reinterpret_cast<const float4*>(g + (lane << 2));
      rb[rr] = *reinterpret_cast<const float4*>(g + 256 + (lane << 2));
    }
  }
  __syncthreads();

  for (int c = 0; c < 128; ++c) {
    if (wv > 0) {
      if (c + 1 < 128) {  // write chunk c+1 (regs loaded during iter c-1)
        const int nb = (c + 1) & 1;
#pragma unroll
        for (int rr = 0; rr < 8; ++rr) {
          float* l = &buf[nb][r0 + rr][0];
          *reinterpret_cast<float4*>(l + (pA << 2)) = ra[rr];
          *reinterpret_cast<float4*>(l + (pB << 2)) = rb[rr];
        }
      }
      if (c + 2 < 128) {  // issue loads for chunk c+2
        const float* cb = base + ((size_t)(c + 2) * 16 + r0) * NS_;
#pragma unroll
        for (int rr = 0; rr < 8; ++rr) {
          const float* g = cb + (size_t)rr * NS_;
          ra[rr] = *reinterpret_cast<const float4*>(g + (lane << 2));
          rb[rr] = *reinterpret_cast<const float4*>(g + 256 + (lane << 2));
        }
      }
    } else {
      const float* rowbase = &buf[c & 1][0][0];
      const int tbase = c << 4;
      if (c < 32) {
        DP_CHUNK(true)
      } else {
        DP_CHUNK(false)
      }
      if (c & 1) {  // 32 rows accumulated -> store direction words
        const int c32 = c >> 1;
#pragma unroll
        for (int j = 0; j < 8; ++j) {
          dir[((size_t)(b * NS_) + (lane << 3) + j) * 64 + c32] = bw[j];
          bw[j] = 0u;
        }
      }
    }
    __syncthreads();
  }
}

// ---------------- backtrack (two half-T phases) ----------------
__global__ __launch_bounds__(256) void k_backtrack(
    const uint32_t* __restrict__ dir, const int* __restrict__ src_len,
    const int* __restrict__ mel_len, float* __restrict__ hard,
    int* __restrict__ idxio, int phase) {
  __shared__ uint32_t dl[NS_ * 32];
  const int b = blockIdx.x, tid = threadIdx.x;
  const uint32_t* db = dir + (size_t)b * NS_ * 64;
  const int woff = phase ? 0 : 32;
  for (int f = tid; f < 4096; f += 256) {
    int s = f >> 3;
    int wo = (f & 7) << 2;
    *reinterpret_cast<uint4*>(&dl[s * 32 + wo]) =
        *reinterpret_cast<const uint4*>(&db[s * 64 + woff + wo]);
  }
  __syncthreads();
  if (tid == 0) {
    const int ml = mel_len[b];
    int idx = phase ? idxio[b] : (src_len[b] - 1);
    if (idx < 0) idx = 0;
    if (idx > NS_ - 1) idx = NS_ - 1;
    const int thi = phase ? 1023 : 2047;
    const int tlo = phase ? 0 : 1024;
    int cw = -1, ci = -1;
    uint32_t w = 0;
    for (int t = thi; t >= tlo; --t) {
      int wi = t >> 5;
      if (wi != cw || idx != ci) {
        w = dl[idx * 32 + (wi - woff)];
        cw = wi;
        ci = idx;
      }
      if (t < ml) hard[((size_t)(b * NS_) + idx) * NT_ + t] = 1.0f;
      int step = (int)((w >> (t & 31)) & 1) - 1;
      idx += step;
      if (idx < 0) idx = 0;
    }
    if (!phase) idxio[b] = idx;
  }
}

// ---------------- host launch ----------------
extern "C" void kernel_launch(void* const* d_in, const int* in_sizes, int n_in,
                              void* d_out, int out_size, void* d_ws, size_t ws_size,
                              hipStream_t stream) {
  if (n_in != 17) return;
  if (ws_size < FULL_NEED) return;

  const void* text = d_in[0];
  const void* mel = d_in[1];
  const int* src_len = (const int*)d_in[2];
  const int* mel_len = (const int*)d_in[3];
  const void* tw1 = d_in[7];
  const void* tb1 = d_in[8];
  const void* tw2 = d_in[9];
  const void* tb2 = d_in[10];
  const void* mw1 = d_in[11];
  const void* mb1 = d_in[12];
  const void* mw2 = d_in[13];
  const void* mb2 = d_in[14];
  const void* mw3 = d_in[15];
  const void* mb3 = d_in[16];

  char* w8 = (char*)d_ws;
  float* mel_f32 = (float*)(w8 + 0);
  float* melh1 = (float*)(w8 + 20971520ull);
  float* mh2 = (float*)(w8 + 62914560ull);
  float* text_f32 = (float*)(w8 + 83886080ull);
  float* texth1 = (float*)(w8 + 100663296ull);
  float* val = (float*)(w8 + 0);

  float* te = (float*)(w8 + P + PO_TE);
  float* me = (float*)(w8 + P + PO_ME);
  float* na = (float*)(w8 + P + PO_NA);
  float* nb = (float*)(w8 + P + PO_NB);
  float* marr = (float*)(w8 + P + PO_M);
  float* rzarr = (float*)(w8 + P + PO_RZ);
  float* wt1 = (float*)(w8 + P + PO_W1);
  float* wt2 = (float*)(w8 + P + PO_W2);
  float* wt3 = (float*)(w8 + P + PO_W3);
  float* wt4 = (float*)(w8 + P + PO_W4);
  float* wt5 = (float*)(w8 + P + PO_W5);
  float* biasb = (float*)(w8 + P + PO_BIAS);
  uint32_t* dir = (uint32_t*)(w8 + P + PO_DIR);
  int* idxio = (int*)(w8 + P + PO_IDX);
  int* flag = (int*)(w8 + P + PO_FLAG);

  // outputs are float32
  float* soft = (float*)d_out;
  float* hard = soft + (size_t)NB_ * NS_ * NT_;
  float* rev = soft + 2 * (size_t)NB_ * NS_ * NT_;

  // dtype detect + converts
  k_detect<<<1, 256, 0, stream>>>((const uint32_t*)text, flag);
  k_cvt<<<(NB_ * NS_ * 256 + 255) / 256, 256, 0, stream>>>(text, text_f32, NB_ * NS_ * 256, flag);
  k_cvt<<<(NB_ * NT_ * 80 + 255) / 256, 256, 0, stream>>>(mel, mel_f32, NB_ * NT_ * 80, flag);
  k_cvt<<<2, 256, 0, stream>>>(tb1, biasb + BO_T1, 512, flag);
  k_cvt<<<1, 256, 0, stream>>>(tb2, biasb + BO_T2, 80, flag);
  k_cvt<<<1, 256, 0, stream>>>(mb1, biasb + BO_M1, 160, flag);
  k_cvt<<<1, 256, 0, stream>>>(mb2, biasb + BO_M2, 80, flag);
  k_cvt<<<1, 256, 0, stream>>>(mb3, biasb + BO_M3, 80, flag);

  // weight transposes
  k_wtrans<<<(512 * 256 * 3 + 255) / 256, 256, 0, stream>>>(tw1, wt1, 512, 256, 3, 512 * 256 * 3, flag);
  k_wtrans<<<(80 * 512 + 255) / 256, 256, 0, stream>>>(tw2, wt2, 80, 512, 1, 80 * 512, flag);
  k_wtrans<<<(160 * 80 * 3 + 255) / 256, 256, 0, stream>>>(mw1, wt3, 160, 80, 3, 160 * 80 * 3, flag);
  k_wtrans<<<(80 * 160 * 3 + 255) / 256, 256, 0, stream>>>(mw2, wt4, 80, 160, 3, 80 * 160 * 3, flag);
  k_wtrans<<<(80 * 80 + 255) / 256, 256, 0, stream>>>(mw3, wt5, 80, 80, 1, 80 * 80, flag);

  // encoders (pure f32)
  k_conv<80, 3, 160, 80, 5, 16, 11, 2, false><<<512 * 2, 256, 0, stream>>>(mel_f32, wt3, biasb + BO_M1, melh1, nullptr);
  k_conv<160, 3, 80, 80, 5, 32, 11, 2, false><<<512 * 1, 256, 0, stream>>>(melh1, wt4, biasb + BO_M2, mh2, nullptr);
  k_conv<80, 1, 80, 80, 5, 16, 11, 0, true><<<512 * 1, 256, 0, stream>>>(mh2, wt5, biasb + BO_M3, me, mel_len);
  k_conv<256, 3, 512, 128, 8, 32, 9, 1, false><<<128 * 4, 256, 0, stream>>>(text_f32, wt1, biasb + BO_T1, texth1, nullptr);
  k_conv<512, 1, 80, 80, 5, 32, 9, 0, true><<<128 * 1, 256, 0, stream>>>(texth1, wt2, biasb + BO_T2, te, src_len);

  // norms
  k_norms<<<(NB_ * NS_ * 4) / 256, 256, 0, stream>>>(te, na, NB_ * NS_);
  k_norms<<<(NB_ * NT_ * 4) / 256, 256, 0, stream>>>(me, nb, NB_ * NT_);

  // softmax stats + finalize
  k_stats2<<<NB_ * 32, 256, 0, stream>>>(te, me, na, nb, src_len, mel_len, marr, rzarr);
  k_final3<<<NB_ * 8 * 32, 256, 0, stream>>>(te, me, na, nb, marr, rzarr, src_len, mel_len,
                                             val, soft, rev);

  // hard_A
  hipMemsetAsync(hard, 0, (size_t)NB_ * NS_ * NT_ * 4, stream);
  k_dp<<<NB_, 192, 0, stream>>>(val, src_len, mel_len, dir);
  k_backtrack<<<NB_, 256, 0, stream>>>(dir, src_len, mel_len, hard, idxio, 0);
  k_backtrack<<<NB_, 256, 0, stream>>>(dir, src_len, mel_len, hard, idxio, 1);
}

// Round 11
// 1337.857 us; speedup vs baseline: 1.0852x; 1.0087x over previous
//
#include <hip/hip_runtime.h>
#include <hip/hip_bf16.h>
#include <cstdint>

// Problem constants
constexpr int NB_ = 32;     // batch
constexpr int NS_ = 512;    // text length S
constexpr int NT_ = 2048;   // mel length T
constexpr int DMEL = 80;    // embedding dim

// ---------------- workspace layout ----------------
constexpr size_t P = 134217728ull;  // persistent block base
constexpr size_t PO_TE   = 0ull;
constexpr size_t PO_ME   = 5242880ull;
constexpr size_t PO_NA   = 26214400ull;
constexpr size_t PO_NB   = 26279936ull;
constexpr size_t PO_M    = 26542080ull;
constexpr size_t PO_RZ   = 26804224ull;
constexpr size_t PO_W1   = 27066368ull;
constexpr size_t PO_W2   = 28639232ull;
constexpr size_t PO_W3   = 28803072ull;
constexpr size_t PO_W4   = 28956672ull;
constexpr size_t PO_W5   = 29110272ull;
constexpr size_t PO_BIAS = 29135872ull;
constexpr size_t PO_DIR  = 29139968ull;
constexpr size_t PO_IDX  = 33334272ull;
constexpr size_t PO_FLAG = 33334400ull;
constexpr size_t FULL_NEED = P + 33334528ull;

constexpr int BO_T1 = 0, BO_T2 = 512, BO_M1 = 592, BO_M2 = 752, BO_M3 = 832;

// ---------------- dtype detect: bf16 vs f32 probe on text ----------------
__global__ void k_detect(const uint32_t* __restrict__ w, int* __restrict__ flag) {
  __shared__ int red[256];
  const int tid = threadIdx.x;
  int cnt = 0;
  for (int i = tid; i < 4096; i += 256) {
    uint32_t e = (w[i] >> 7) & 0xFFu;
    cnt += (e >= 119u && e <= 129u) ? 1 : 0;
  }
  red[tid] = cnt;
  __syncthreads();
  for (int s = 128; s > 0; s >>= 1) {
    if (tid < s) red[tid] += red[tid + s];
    __syncthreads();
  }
  if (tid == 0) *flag = (red[0] > 2048) ? 1 : 0;
}

// ---------------- flag-branched convert to f32 ----------------
__global__ void k_cvt(const void* __restrict__ in, float* __restrict__ out, int n,
                      const int* __restrict__ flag) {
  const int i = blockIdx.x * 256 + threadIdx.x;
  if (i >= n) return;
  if (*flag) {
    uint16_t u = ((const uint16_t*)in)[i];
    out[i] = __uint_as_float((uint32_t)u << 16);
  } else {
    out[i] = ((const float*)in)[i];
  }
}

// ---------------- weight transpose ----------------
__global__ void k_wtrans(const void* __restrict__ w, float* __restrict__ wT,
                         int CO, int CI, int KW, int total, const int* __restrict__ flag) {
  int id = blockIdx.x * 256 + threadIdx.x;
  if (id >= total) return;
  int co = id % CO;
  int rest = id / CO;
  int ci = rest % CI;
  int tap = rest / CI;
  int src = (co * CI + ci) * KW + tap;
  if (*flag) {
    uint16_t u = ((const uint16_t*)w)[src];
    wT[id] = __uint_as_float((uint32_t)u << 16);
  } else {
    wT[id] = ((const float*)w)[src];
  }
}

// ---------------- conv1d as implicit GEMM (pure f32) ----------------
template <int CIN, int KW, int COUT, int NTILE, int NR, int KC, int LOG2L, int ACT, bool MASK>
__global__ __launch_bounds__(256) void k_conv(const float* __restrict__ x,
                                              const float* __restrict__ wT,
                                              const float* __restrict__ bias,
                                              float* __restrict__ y,
                                              const int* __restrict__ lenArr) {
  constexpr int L = 1 << LOG2L;
  constexpr int PAD = (KW - 1) / 2;
  constexpr int MT = 128;
  constexpr int APAD = 132;
  constexpr int BPAD = NTILE + 4;
  __shared__ float As[KC][APAD];
  __shared__ float Bs[KC][BPAD];

  const int tid = threadIdx.x;
  const int tx = tid & 15;
  const int ty = tid >> 4;
  constexpr int NBLK = COUT / NTILE;
  const int m0 = (blockIdx.x / NBLK) * MT;
  const int n0 = (blockIdx.x % NBLK) * NTILE;

  float acc[8][NR];
#pragma unroll
  for (int i = 0; i < 8; ++i)
#pragma unroll
    for (int j = 0; j < NR; ++j) acc[i][j] = 0.f;

  for (int tap = 0; tap < KW; ++tap) {
    for (int k0 = 0; k0 < CIN; k0 += KC) {
      __syncthreads();
      constexpr int AF4 = MT * KC / 4;
      constexpr int F4R = KC / 4;
      for (int f = tid; f < AF4; f += 256) {
        int row = f / F4R;
        int ko = (f % F4R) * 4;
        int r = m0 + row;
        int b = r >> LOG2L;
        int pos = (r & (L - 1)) + tap - PAD;
        float4 v = make_float4(0.f, 0.f, 0.f, 0.f);
        if (pos >= 0 && pos < L)
          v = *reinterpret_cast<const float4*>(
              &x[((size_t)(b << LOG2L) + pos) * CIN + k0 + ko]);
        As[ko + 0][row] = v.x;
        As[ko + 1][row] = v.y;
        As[ko + 2][row] = v.z;
        As[ko + 3][row] = v.w;
      }
      constexpr int BF4 = KC * NTILE / 4;
      constexpr int BF4R = NTILE / 4;
      for (int f = tid; f < BF4; f += 256) {
        int kk = f / BF4R;
        int no = (f % BF4R) * 4;
        float4 v = *reinterpret_cast<const float4*>(
            &wT[((size_t)(tap * CIN + k0 + kk)) * COUT + n0 + no]);
        *reinterpret_cast<float4*>(&Bs[kk][no]) = v;
      }
      __syncthreads();
#pragma unroll 8
      for (int kk = 0; kk < KC; ++kk) {
        float4 a0 = *reinterpret_cast<const float4*>(&As[kk][ty * 8]);
        float4 a1 = *reinterpret_cast<const float4*>(&As[kk][ty * 8 + 4]);
        float av[8] = {a0.x, a0.y, a0.z, a0.w, a1.x, a1.y, a1.z, a1.w};
        float bv[NR];
#pragma unroll
        for (int j = 0; j < NR; ++j) bv[j] = Bs[kk][tx * NR + j];
#pragma unroll
        for (int i = 0; i < 8; ++i)
#pragma unroll
          for (int j = 0; j < NR; ++j) acc[i][j] = fmaf(av[i], bv[j], acc[i][j]);
      }
    }
  }
#pragma unroll
  for (int i = 0; i < 8; ++i) {
    int r = m0 + ty * 8 + i;
    int b = r >> LOG2L;
    int pos = r & (L - 1);
    bool zero = MASK && (pos >= lenArr[b]);
#pragma unroll
    for (int j = 0; j < NR; ++j) {
      int c = n0 + tx * NR + j;
      float v = acc[i][j] + bias[c];
      if (ACT == 1) v = fmaxf(v, 0.f);
      if (ACT == 2) v = (v >= 0.f) ? v : 0.01f * v;
      if (zero) v = 0.f;
      y[(size_t)r * COUT + c] = v;
    }
  }
}

// ---------------- row squared-norms ----------------
__global__ void k_norms(const float* __restrict__ e, float* __restrict__ out, int rows) {
  int tid = blockIdx.x * 256 + threadIdx.x;
  int row = tid >> 2, sub = tid & 3;
  if (row >= rows) return;
  const float* p = e + (size_t)row * DMEL;
  float s = 0.f;
#pragma unroll
  for (int j = 0; j < 5; ++j) {
    float4 v = *reinterpret_cast<const float4*>(&p[(sub + 4 * j) * 4]);
    s = fmaf(v.x, v.x, fmaf(v.y, v.y, fmaf(v.z, v.z, fmaf(v.w, v.w, s))));
  }
  s += __shfl_xor(s, 1);
  s += __shfl_xor(s, 2);
  if (sub == 0) out[row] = s;
}

// ---------------- softmax stats by recomputation ----------------
__global__ __launch_bounds__(256) void k_stats2(
    const float* __restrict__ te, const float* __restrict__ me,
    const float* __restrict__ na, const float* __restrict__ nb,
    const int* __restrict__ src_len, const int* __restrict__ mel_len,
    float* __restrict__ marr, float* __restrict__ rzarr) {
  const int b = blockIdx.x >> 5;
  const int t0 = (blockIdx.x & 31) << 6;
  __shared__ float Bt[DMEL][68];
  __shared__ float At[DMEL][68];
  __shared__ float redm[16][64];
  __shared__ float redz[16][64];
  const int tid = threadIdx.x;
  for (int f = tid; f < 64 * 20; f += 256) {
    int row = f / 20, ko = (f % 20) << 2;
    float4 v = *reinterpret_cast<const float4*>(
        &me[((size_t)b * NT_ + t0 + row) * DMEL + ko]);
    Bt[ko][row] = v.x; Bt[ko + 1][row] = v.y; Bt[ko + 2][row] = v.z; Bt[ko + 3][row] = v.w;
  }
  const int tx = tid & 15, sy = tid >> 4;
  const int sl = src_len[b], ml = mel_len[b];
  const float NEGINF = -__builtin_inff();
  float nbv[4], mACC[4], zACC[4];
#pragma unroll
  for (int j = 0; j < 4; ++j) {
    nbv[j] = nb[b * NT_ + t0 + (tx << 2) + j];
    mACC[j] = NEGINF;
    zACC[j] = 0.f;
  }
  for (int c = 0; c < 8; ++c) {
    const int s0 = c << 6;
    __syncthreads();
    for (int f = tid; f < 64 * 20; f += 256) {
      int row = f / 20, ko = (f % 20) << 2;
      float4 v = *reinterpret_cast<const float4*>(
          &te[((size_t)b * NS_ + s0 + row) * DMEL + ko]);
      At[ko][row] = v.x; At[ko + 1][row] = v.y; At[ko + 2][row] = v.z; At[ko + 3][row] = v.w;
    }
    __syncthreads();
    float acc[4][4];
#pragma unroll
    for (int i = 0; i < 4; ++i)
#pragma unroll
      for (int j = 0; j < 4; ++j) acc[i][j] = 0.f;
#pragma unroll 8
    for (int kk = 0; kk < DMEL; ++kk) {
      float4 a = *reinterpret_cast<const float4*>(&At[kk][sy << 2]);
      float4 bb = *reinterpret_cast<const float4*>(&Bt[kk][tx << 2]);
      float av[4] = {a.x, a.y, a.z, a.w}, bv[4] = {bb.x, bb.y, bb.z, bb.w};
#pragma unroll
      for (int i = 0; i < 4; ++i)
#pragma unroll
        for (int j = 0; j < 4; ++j) acc[i][j] = fmaf(av[i], bv[j], acc[i][j]);
    }
    float nav[4];
#pragma unroll
    for (int i = 0; i < 4; ++i) nav[i] = na[b * NS_ + s0 + (sy << 2) + i];
#pragma unroll
    for (int j = 0; j < 4; ++j) {
      const bool tvalid = (t0 + (tx << 2) + j) < ml;
      float ov[4];
      float mNew = mACC[j];
#pragma unroll
      for (int i = 0; i < 4; ++i) {
        float d2 = (nav[i] + nbv[j]) - 2.0f * acc[i][j];
        float dist = sqrtf(fmaxf(d2, 1e-12f));
        bool valid = ((s0 + (sy << 2) + i) < sl) && tvalid;
        ov[i] = valid ? -dist : -1e9f;
        mNew = fmaxf(mNew, ov[i]);
      }
      float scale = expf(mACC[j] - mNew);
      float zadd = 0.f;
#pragma unroll
      for (int i = 0; i < 4; ++i) zadd += expf(ov[i] - mNew);
      zACC[j] = zACC[j] * scale + zadd;
      mACC[j] = mNew;
    }
  }
#pragma unroll
  for (int j = 0; j < 4; ++j) {
    redm[sy][(tx << 2) + j] = mACC[j];
    redz[sy][(tx << 2) + j] = zACC[j];
  }
  __syncthreads();
  if (tid < 64) {
    float M = NEGINF, Z = 0.f;
#pragma unroll
    for (int y = 0; y < 16; ++y) {
      float m = redm[y][tid], z = redz[y][tid];
      float Mn = fmaxf(M, m);
      Z = Z * expf(M - Mn) + z * expf(m - Mn);
      M = Mn;
    }
    marr[b * NT_ + t0 + tid] = M;
    rzarr[b * NT_ + t0 + tid] = 1.0f / Z;
  }
}

// ---------------- finalize: soft/rev f32 out + f32 val for DP ----------------
__global__ __launch_bounds__(256) void k_final3(
    const float* __restrict__ te, const float* __restrict__ me,
    const float* __restrict__ na, const float* __restrict__ nb,
    const float* __restrict__ marr, const float* __restrict__ rzarr,
    const int* __restrict__ src_len, const int* __restrict__ mel_len,
    float* __restrict__ val,
    float* __restrict__ soft, float* __restrict__ rev) {
  const int idx = blockIdx.x;
  const int tt = idx & 31;
  const int st = (idx >> 5) & 7;
  const int b = idx >> 8;
  const int s0 = st << 6, t0 = tt << 6;
  __shared__ float At[DMEL][68];
  __shared__ float Bt[DMEL][68];
  __shared__ float pl[64][65];
  const int tid = threadIdx.x;
  for (int f = tid; f < 64 * 20; f += 256) {
    int row = f / 20, ko = (f % 20) << 2;
    float4 v = *reinterpret_cast<const float4*>(
        &te[((size_t)b * NS_ + s0 + row) * DMEL + ko]);
    At[ko][row] = v.x; At[ko + 1][row] = v.y; At[ko + 2][row] = v.z; At[ko + 3][row] = v.w;
  }
  for (int f = tid; f < 64 * 20; f += 256) {
    int row = f / 20, ko = (f % 20) << 2;
    float4 v = *reinterpret_cast<const float4*>(
        &me[((size_t)b * NT_ + t0 + row) * DMEL + ko]);
    Bt[ko][row] = v.x; Bt[ko + 1][row] = v.y; Bt[ko + 2][row] = v.z; Bt[ko + 3][row] = v.w;
  }
  __syncthreads();
  const int tx = tid & 15, sy = tid >> 4;
  float acc[4][4];
#pragma unroll
  for (int i = 0; i < 4; ++i)
#pragma unroll
    for (int j = 0; j < 4; ++j) acc[i][j] = 0.f;
#pragma unroll 8
  for (int kk = 0; kk < DMEL; ++kk) {
    float4 a = *reinterpret_cast<const float4*>(&At[kk][sy << 2]);
    float4 bb = *reinterpret_cast<const float4*>(&Bt[kk][tx << 2]);
    float av[4] = {a.x, a.y, a.z, a.w}, bv[4] = {bb.x, bb.y, bb.z, bb.w};
#pragma unroll
    for (int i = 0; i < 4; ++i)
#pragma unroll
      for (int j = 0; j < 4; ++j) acc[i][j] = fmaf(av[i], bv[j], acc[i][j]);
  }
  const int sl = src_len[b], ml = mel_len[b];
  float nav[4], nbv[4];
#pragma unroll
  for (int i = 0; i < 4; ++i) nav[i] = na[b * NS_ + s0 + (sy << 2) + i];
#pragma unroll
  for (int j = 0; j < 4; ++j) nbv[j] = nb[b * NT_ + t0 + (tx << 2) + j];
#pragma unroll
  for (int j = 0; j < 4; ++j) {
    const int t = t0 + (tx << 2) + j;
    const bool tvalid = t < ml;
    const float mv = marr[b * NT_ + t];
    const float rzv = rzarr[b * NT_ + t];
    float pv[4];
#pragma unroll
    for (int i = 0; i < 4; ++i) {
      float d2 = (nav[i] + nbv[j]) - 2.0f * acc[i][j];
      float dist = sqrtf(fmaxf(d2, 1e-12f));
      bool valid = ((s0 + (sy << 2) + i) < sl) && tvalid;
      float ov = valid ? -dist : -1e9f;
      float p = tvalid ? expf(ov - mv) * rzv : 0.f;
      pv[i] = p;
      pl[(tx << 2) + j][(sy << 2) + i] = p;
    }
    float4 o = make_float4(pv[0], pv[1], pv[2], pv[3]);
    *reinterpret_cast<float4*>(&val[((size_t)b * NT_ + t) * NS_ + s0 + (sy << 2)]) = o;
  }
  __syncthreads();
  const int lane = tid & 63, w = tid >> 6;
#pragma unroll 4
  for (int i = 0; i < 16; ++i) {
    const int s_loc = (w << 4) + i;
    const int s = s0 + s_loc;
    float p = pl[lane][s_loc];
    size_t o = ((size_t)b * NS_ + s) * NT_ + t0 + lane;
    soft[o] = p;
    bool r = (s >= sl) || ((t0 + lane) >= ml);
    rev[o] = r ? 1.0f : 0.0f;
  }
}

// lane i <- lane i-1 via DPP wave_shr:1 (VALU, no LDS pipe). Lane 0 -> 0.
__device__ __forceinline__ float dp_shr1(float x) {
  int r = __builtin_amdgcn_update_dpp(0, __float_as_int(x), 0x138, 0xF, 0xF, true);
  return __int_as_float(r);
}

// Consumer chunk body: 16 rows, 4-row register batches. MASKED = apply (s<=t).
#define DP_CHUNK(MASKED)                                                      \
  _Pragma("unroll")                                                           \
  for (int rb8 = 0; rb8 < 4; ++rb8) {                                         \
    float4 d0[4], d1[4];                                                      \
    _Pragma("unroll")                                                         \
    for (int rr = 0; rr < 4; ++rr) {                                          \
      const float* rp = rowbase + (((rb8 << 2) + rr) << 9);                   \
      d0[rr] = *reinterpret_cast<const float4*>(rp + (lane << 2));            \
      d1[rr] = *reinterpret_cast<const float4*>(rp + 256 + (lane << 2));      \
    }                                                                         \
    _Pragma("unroll")                                                         \
    for (int rr = 0; rr < 4; ++rr) {                                          \
      const int t = tbase + (rb8 << 2) + rr;                                  \
      float cc[8] = {d0[rr].x, d0[rr].y, d0[rr].z, d0[rr].w,                  \
                     d1[rr].x, d1[rr].y, d1[rr].z, d1[rr].w};                 \
      const int sh = t & 31;                                                  \
      if (t < ml) {                                                           \
        float up = dp_shr1(v[7]);                                             \
        float prev = (lane == 0) ? NEGINF : up;                               \
        _Pragma("unroll")                                                     \
        for (int j = 0; j < 8; ++j) {                                         \
          float cur = v[j];                                                   \
          bool keep = cur >= prev;                                            \
          float vm = fmaxf(cur, prev);                                        \
          float vn;                                                           \
          if (MASKED) {                                                       \
            int s = (lane << 3) + j;                                          \
            vn = (s <= t) ? vm + cc[j] : NEGINF;                              \
          } else {                                                            \
            vn = vm + cc[j];                                                  \
          }                                                                   \
          uint32_t bit = keep ? 1u : inv[j];                                  \
          bw[j] |= bit << sh;                                                 \
          v[j] = vn;                                                          \
          prev = cur;                                                         \
        }                                                                     \
      } else {                                                                \
        _Pragma("unroll")                                                     \
        for (int j = 0; j < 8; ++j) bw[j] |= 1u << sh;                        \
      }                                                                       \
    }                                                                         \
  }

// ---------------- DP forward scan: 1 consumer + 2 reg-staging producer waves ----
// De-interleave moved into the GLOBAL load addresses (rule 21): lane l loads
// floats [8l..8l+3] and [8l+4..8l+7] (stride-32B, both instructions together
// cover each 64B line), then writes LDS at float offsets 4l and 256+4l --
// byte-identical to the measured-conflict-free consumer read pattern.
// Loads for chunk c+2 issued at iter c, written at iter c+1 (full-iteration
// latency slack). Rows t>=ml short-circuit to all-1 direction bits.
__global__ __launch_bounds__(192) void k_dp(const float* __restrict__ val,
                                            const int* __restrict__ src_len,
                                            const int* __restrict__ mel_len,
                                            uint32_t* __restrict__ dir) {
  __shared__ float buf[2][16][512];  // 64 KB double buffer
  const int b = blockIdx.x;
  const int wv = threadIdx.x >> 6;   // 0 = consumer, 1..2 = producers
  const int lane = threadIdx.x & 63;
  const float* base = val + (size_t)b * NT_ * NS_;
  const int sl = src_len[b];
  const int ml = mel_len[b];
  const float NEGINF = -__builtin_inff();

  // producer state: 8 rows per producer wave
  float4 ra[8], rb[8];
  const int r0 = (wv - 1) << 3;

  // consumer state
  float v[8];
  uint32_t bw[8], inv[8];
#pragma unroll
  for (int j = 0; j < 8; ++j) {
    v[j] = 0.0f;
    bw[j] = 0u;
    int s = (lane << 3) + j;
    inv[j] = (s < sl) ? 0u : 1u;
  }

  if (wv > 0) {
    // stage chunk 0 into buf0; preload chunk 1 into regs
#pragma unroll
    for (int rr = 0; rr < 8; ++rr) {
      const float* g = base + (size_t)(r0 + rr) * NS_;
      ra[rr] = *reinterpret_cast<const float4*>(g + (lane << 3));
      rb[rr] = *reinterpret_cast<const float4*>(g + (lane << 3) + 4);
    }
#pragma unroll
    for (int rr = 0; rr < 8; ++rr) {
      float* l = &buf[0][r0 + rr][0];
      *reinterpret_cast<float4*>(l + (lane << 2)) = ra[rr];
      *reinterpret_cast<float4*>(l + 256 + (lane << 2)) = rb[rr];
    }
#pragma unroll
    for (int rr = 0; rr < 8; ++rr) {
      const float* g = base + (size_t)(16 + r0 + rr) * NS_;
      ra[rr] = *reinterpret_cast<const float4*>(g + (lane << 3));
      rb[rr] = *reinterpret_cast<const float4*>(g + (lane << 3) + 4);
    }
  }
  __syncthreads();

  for (int c = 0; c < 128; ++c) {
    if (wv > 0) {
      if (c + 1 < 128) {  // write chunk c+1 (regs loaded during iter c-1)
        const int nb = (c + 1) & 1;
#pragma unroll
        for (int rr = 0; rr < 8; ++rr) {
          float* l = &buf[nb][r0 + rr][0];
          *reinterpret_cast<float4*>(l + (lane << 2)) = ra[rr];
          *reinterpret_cast<float4*>(l + 256 + (lane << 2)) = rb[rr];
        }
      }
      if (c + 2 < 128) {  // issue loads for chunk c+2
        const float* cb = base + ((size_t)(c + 2) * 16 + r0) * NS_;
#pragma unroll
        for (int rr = 0; rr < 8; ++rr) {
          const float* g = cb + (size_t)rr * NS_;
          ra[rr] = *reinterpret_cast<const float4*>(g + (lane << 3));
          rb[rr] = *reinterpret_cast<const float4*>(g + (lane << 3) + 4);
        }
      }
    } else {
      const float* rowbase = &buf[c & 1][0][0];
      const int tbase = c << 4;
      if (c < 32) {
        DP_CHUNK(true)
      } else {
        DP_CHUNK(false)
      }
      if (c & 1) {  // 32 rows accumulated -> store direction words
        const int c32 = c >> 1;
#pragma unroll
        for (int j = 0; j < 8; ++j) {
          dir[((size_t)(b * NS_) + (lane << 3) + j) * 64 + c32] = bw[j];
          bw[j] = 0u;
        }
      }
    }
    __syncthreads();
  }
}

// ---------------- backtrack (two half-T phases) ----------------
__global__ __launch_bounds__(256) void k_backtrack(
    const uint32_t* __restrict__ dir, const int* __restrict__ src_len,
    const int* __restrict__ mel_len, float* __restrict__ hard,
    int* __restrict__ idxio, int phase) {
  __shared__ uint32_t dl[NS_ * 32];
  const int b = blockIdx.x, tid = threadIdx.x;
  const uint32_t* db = dir + (size_t)b * NS_ * 64;
  const int woff = phase ? 0 : 32;
  for (int f = tid; f < 4096; f += 256) {
    int s = f >> 3;
    int wo = (f & 7) << 2;
    *reinterpret_cast<uint4*>(&dl[s * 32 + wo]) =
        *reinterpret_cast<const uint4*>(&db[s * 64 + woff + wo]);
  }
  __syncthreads();
  if (tid == 0) {
    const int ml = mel_len[b];
    int idx = phase ? idxio[b] : (src_len[b] - 1);
    if (idx < 0) idx = 0;
    if (idx > NS_ - 1) idx = NS_ - 1;
    const int thi = phase ? 1023 : 2047;
    const int tlo = phase ? 0 : 1024;
    int cw = -1, ci = -1;
    uint32_t w = 0;
    for (int t = thi; t >= tlo; --t) {
      int wi = t >> 5;
      if (wi != cw || idx != ci) {
        w = dl[idx * 32 + (wi - woff)];
        cw = wi;
        ci = idx;
      }
      if (t < ml) hard[((size_t)(b * NS_) + idx) * NT_ + t] = 1.0f;
      int step = (int)((w >> (t & 31)) & 1) - 1;
      idx += step;
      if (idx < 0) idx = 0;
    }
    if (!phase) idxio[b] = idx;
  }
}

// ---------------- host launch ----------------
extern "C" void kernel_launch(void* const* d_in, const int* in_sizes, int n_in,
                              void* d_out, int out_size, void* d_ws, size_t ws_size,
                              hipStream_t stream) {
  if (n_in != 17) return;
  if (ws_size < FULL_NEED) return;

  const void* text = d_in[0];
  const void* mel = d_in[1];
  const int* src_len = (const int*)d_in[2];
  const int* mel_len = (const int*)d_in[3];
  const void* tw1 = d_in[7];
  const void* tb1 = d_in[8];
  const void* tw2 = d_in[9];
  const void* tb2 = d_in[10];
  const void* mw1 = d_in[11];
  const void* mb1 = d_in[12];
  const void* mw2 = d_in[13];
  const void* mb2 = d_in[14];
  const void* mw3 = d_in[15];
  const void* mb3 = d_in[16];

  char* w8 = (char*)d_ws;
  float* mel_f32 = (float*)(w8 + 0);
  float* melh1 = (float*)(w8 + 20971520ull);
  float* mh2 = (float*)(w8 + 62914560ull);
  float* text_f32 = (float*)(w8 + 83886080ull);
  float* texth1 = (float*)(w8 + 100663296ull);
  float* val = (float*)(w8 + 0);

  float* te = (float*)(w8 + P + PO_TE);
  float* me = (float*)(w8 + P + PO_ME);
  float* na = (float*)(w8 + P + PO_NA);
  float* nb = (float*)(w8 + P + PO_NB);
  float* marr = (float*)(w8 + P + PO_M);
  float* rzarr = (float*)(w8 + P + PO_RZ);
  float* wt1 = (float*)(w8 + P + PO_W1);
  float* wt2 = (float*)(w8 + P + PO_W2);
  float* wt3 = (float*)(w8 + P + PO_W3);
  float* wt4 = (float*)(w8 + P + PO_W4);
  float* wt5 = (float*)(w8 + P + PO_W5);
  float* biasb = (float*)(w8 + P + PO_BIAS);
  uint32_t* dir = (uint32_t*)(w8 + P + PO_DIR);
  int* idxio = (int*)(w8 + P + PO_IDX);
  int* flag = (int*)(w8 + P + PO_FLAG);

  // outputs are float32
  float* soft = (float*)d_out;
  float* hard = soft + (size_t)NB_ * NS_ * NT_;
  float* rev = soft + 2 * (size_t)NB_ * NS_ * NT_;

  // dtype detect + converts
  k_detect<<<1, 256, 0, stream>>>((const uint32_t*)text, flag);
  k_cvt<<<(NB_ * NS_ * 256 + 255) / 256, 256, 0, stream>>>(text, text_f32, NB_ * NS_ * 256, flag);
  k_cvt<<<(NB_ * NT_ * 80 + 255) / 256, 256, 0, stream>>>(mel, mel_f32, NB_ * NT_ * 80, flag);
  k_cvt<<<2, 256, 0, stream>>>(tb1, biasb + BO_T1, 512, flag);
  k_cvt<<<1, 256, 0, stream>>>(tb2, biasb + BO_T2, 80, flag);
  k_cvt<<<1, 256, 0, stream>>>(mb1, biasb + BO_M1, 160, flag);
  k_cvt<<<1, 256, 0, stream>>>(mb2, biasb + BO_M2, 80, flag);
  k_cvt<<<1, 256, 0, stream>>>(mb3, biasb + BO_M3, 80, flag);

  // weight transposes
  k_wtrans<<<(512 * 256 * 3 + 255) / 256, 256, 0, stream>>>(tw1, wt1, 512, 256, 3, 512 * 256 * 3, flag);
  k_wtrans<<<(80 * 512 + 255) / 256, 256, 0, stream>>>(tw2, wt2, 80, 512, 1, 80 * 512, flag);
  k_wtrans<<<(160 * 80 * 3 + 255) / 256, 256, 0, stream>>>(mw1, wt3, 160, 80, 3, 160 * 80 * 3, flag);
  k_wtrans<<<(80 * 160 * 3 + 255) / 256, 256, 0, stream>>>(mw2, wt4, 80, 160, 3, 80 * 160 * 3, flag);
  k_wtrans<<<(80 * 80 + 255) / 256, 256, 0, stream>>>(mw3, wt5, 80, 80, 1, 80 * 80, flag);

  // encoders (pure f32)
  k_conv<80, 3, 160, 80, 5, 16, 11, 2, false><<<512 * 2, 256, 0, stream>>>(mel_f32, wt3, biasb + BO_M1, melh1, nullptr);
  k_conv<160, 3, 80, 80, 5, 32, 11, 2, false><<<512 * 1, 256, 0, stream>>>(melh1, wt4, biasb + BO_M2, mh2, nullptr);
  k_conv<80, 1, 80, 80, 5, 16, 11, 0, true><<<512 * 1, 256, 0, stream>>>(mh2, wt5, biasb + BO_M3, me, mel_len);
  k_conv<256, 3, 512, 128, 8, 32, 9, 1, false><<<128 * 4, 256, 0, stream>>>(text_f32, wt1, biasb + BO_T1, texth1, nullptr);
  k_conv<512, 1, 80, 80, 5, 32, 9, 0, true><<<128 * 1, 256, 0, stream>>>(texth1, wt2, biasb + BO_T2, te, src_len);

  // norms
  k_norms<<<(NB_ * NS_ * 4) / 256, 256, 0, stream>>>(te, na, NB_ * NS_);
  k_norms<<<(NB_ * NT_ * 4) / 256, 256, 0, stream>>>(me, nb, NB_ * NT_);

  // hard_A zero EARLY so its 128MB write traffic doesn't evict val from L3
  // between k_final3 and k_dp
  hipMemsetAsync(hard, 0, (size_t)NB_ * NS_ * NT_ * 4, stream);

  // softmax stats + finalize
  k_stats2<<<NB_ * 32, 256, 0, stream>>>(te, me, na, nb, src_len, mel_len, marr, rzarr);
  k_final3<<<NB_ * 8 * 32, 256, 0, stream>>>(te, me, na, nb, marr, rzarr, src_len, mel_len,
                                             val, soft, rev);

  // DP + backtrack
  k_dp<<<NB_, 192, 0, stream>>>(val, src_len, mel_len, dir);
  k_backtrack<<<NB_, 256, 0, stream>>>(dir, src_len, mel_len, hard, idxio, 0);
  k_backtrack<<<NB_, 256, 0, stream>>>(dir, src_len, mel_len, hard, idxio, 1);
}